// Round 5
// baseline (1785.953 us; speedup 1.0000x reference)
//
#include <hip/hip_runtime.h>
#include <math.h>

#define D_MODEL 512
#define D_INNER 1024
#define L_SEQ 1024
#define BSZ 4
#define NROWS (BSZ * L_SEQ) /* 4096 */
#define DT_RANK 32
#define D_STATE 16
#define CHUNK 32
#define NCHUNK (L_SEQ / CHUNK) /* 32 */

typedef unsigned short ushort_t;
typedef __attribute__((ext_vector_type(8))) short short8;
typedef __attribute__((ext_vector_type(4))) float f32x4;

__device__ inline ushort_t bf16_rn(float f) {
    union { float f; unsigned u; } v; v.f = f;
    unsigned r = v.u + 0x7fffu + ((v.u >> 16) & 1u);
    return (ushort_t)(r >> 16);
}
__device__ inline float b2f(ushort_t u) {
    union { unsigned u; float f; } v; v.u = (unsigned)u << 16; return v.f;
}

// ---------------------------------------------------------------------------
// All six weight tensors fp32 -> bf16 in ONE dispatch. Destination segments
// are contiguous in ws in this order: in_w, xproj_w, dtproj_w, out_w, mlp_w1,
// mlp_w2 -> dst uint2 index == global index i.
// ---------------------------------------------------------------------------
#define F2B_TOT 3399680  /* total float4 groups across all 6 weight tensors */
__global__ __launch_bounds__(256) void f2b_all_kernel(
    const float* __restrict__ w0, const float* __restrict__ w1,
    const float* __restrict__ w2, const float* __restrict__ w3,
    const float* __restrict__ w4, const float* __restrict__ w5,
    ushort_t* __restrict__ dst) {
    int i = blockIdx.x * 256 + threadIdx.x;
    if (i >= F2B_TOT) return;
    const float* src; int j;
    if (i < 1310720)      { src = w0; j = i; }
    else if (i < 1392640) { src = w1; j = i - 1310720; }
    else if (i < 1433600) { src = w2; j = i - 1392640; }
    else if (i < 2088960) { src = w3; j = i - 1433600; }
    else if (i < 2744320) { src = w4; j = i - 2088960; }
    else                  { src = w5; j = i - 2744320; }
    float4 v = ((const float4*)src)[j];
    uint2 pk;
    pk.x = (unsigned)bf16_rn(v.x) | ((unsigned)bf16_rn(v.y) << 16);
    pk.y = (unsigned)bf16_rn(v.z) | ((unsigned)bf16_rn(v.w) << 16);
    ((uint2*)dst)[i] = pk;
}

// ---------------------------------------------------------------------------
// LayerNorm: one wave per row of 512, bf16 output (feeds a GEMM)
// ---------------------------------------------------------------------------
__global__ __launch_bounds__(64) void ln_kernel(const float* __restrict__ x,
                                                const float* __restrict__ g,
                                                const float* __restrict__ b,
                                                ushort_t* __restrict__ out) {
    int row = blockIdx.x;
    int lane = threadIdx.x;
    const float* xr = x + (size_t)row * D_MODEL;
    float4 v0 = *(const float4*)(xr + lane * 8);
    float4 v1 = *(const float4*)(xr + lane * 8 + 4);
    float s = v0.x + v0.y + v0.z + v0.w + v1.x + v1.y + v1.z + v1.w;
    float ss = v0.x * v0.x + v0.y * v0.y + v0.z * v0.z + v0.w * v0.w +
               v1.x * v1.x + v1.y * v1.y + v1.z * v1.z + v1.w * v1.w;
#pragma unroll
    for (int o = 32; o >= 1; o >>= 1) {
        s += __shfl_xor(s, o);
        ss += __shfl_xor(ss, o);
    }
    float mean = s * (1.f / D_MODEL);
    float var = ss * (1.f / D_MODEL) - mean * mean;
    float rstd = rsqrtf(var + 1e-5f);
    float4 g0 = *(const float4*)(g + lane * 8);
    float4 g1 = *(const float4*)(g + lane * 8 + 4);
    float4 b0 = *(const float4*)(b + lane * 8);
    float4 b1 = *(const float4*)(b + lane * 8 + 4);
    float o0 = (v0.x - mean) * rstd * g0.x + b0.x;
    float o1 = (v0.y - mean) * rstd * g0.y + b0.y;
    float o2 = (v0.z - mean) * rstd * g0.z + b0.z;
    float o3 = (v0.w - mean) * rstd * g0.w + b0.w;
    float o4 = (v1.x - mean) * rstd * g1.x + b1.x;
    float o5 = (v1.y - mean) * rstd * g1.y + b1.y;
    float o6 = (v1.z - mean) * rstd * g1.z + b1.z;
    float o7 = (v1.w - mean) * rstd * g1.w + b1.w;
    uint4 pk;
    pk.x = (unsigned)bf16_rn(o0) | ((unsigned)bf16_rn(o1) << 16);
    pk.y = (unsigned)bf16_rn(o2) | ((unsigned)bf16_rn(o3) << 16);
    pk.z = (unsigned)bf16_rn(o4) | ((unsigned)bf16_rn(o5) << 16);
    pk.w = (unsigned)bf16_rn(o6) | ((unsigned)bf16_rn(o7) << 16);
    *(uint4*)(out + (size_t)row * D_MODEL + lane * 8) = pk;
}

// ---------------------------------------------------------------------------
// bf16 MFMA GEMM: C[m,n] = epi( sum_k A[m,k]*W[n,k] ), fp32 accumulate.
// EPI: 0 fp32        1 bias+softplus -> bf16   2 +res fp32
//      3 bias+gelu -> bf16   4 bias+res fp32
//      5 fp32 + bf16 compact copy of cols<32 (dtr)   6 plain bf16
// ---------------------------------------------------------------------------
template <int BMt, int BNt, int EPI>
__global__ __launch_bounds__(256) void bgemm_kernel(
    const ushort_t* __restrict__ A, const ushort_t* __restrict__ W,
    const float* __restrict__ bias, const float* __restrict__ res,
    float* __restrict__ C, ushort_t* __restrict__ Cb,
    int M, int N, int K) {
    constexpr int WM = BMt / 2, WN = BNt / 2;
    constexpr int MT = WM / 16, NT = WN / 16;
    constexpr int ACH = BMt * 4;            // 16B chunks in A tile
    constexpr int TOT = ACH + BNt * 4;
    __shared__ ushort_t As[BMt * 32];
    __shared__ ushort_t Ws[BNt * 32];

    int tid = threadIdx.x;
    int lane = tid & 63;
    int wv = tid >> 6;
    int wrow = wv >> 1, wcol = wv & 1;
    int m0 = blockIdx.y * BMt, n0 = blockIdx.x * BNt;
    int lrow = lane & 15;
    int ko = lane >> 4;

    f32x4 acc[MT][NT] = {};

    for (int k0 = 0; k0 < K; k0 += 32) {
#pragma unroll
        for (int i = 0; i < (TOT + 255) / 256; i++) {
            int e = tid + i * 256;
            if (e < TOT) {
                const ushort_t* gp;
                ushort_t* lp;
                if (e < ACH) {
                    int row = e >> 2, ch = e & 3;
                    gp = A + (size_t)(m0 + row) * K + k0 + ch * 8;
                    lp = As + e * 8;
                } else {
                    int e2 = e - ACH;
                    int row = e2 >> 2, ch = e2 & 3;
                    gp = W + (size_t)(n0 + row) * K + k0 + ch * 8;
                    lp = Ws + e2 * 8;
                }
                __builtin_amdgcn_global_load_lds(
                    (const __attribute__((address_space(1))) void*)gp,
                    (__attribute__((address_space(3))) void*)lp, 16, 0, 0);
            }
        }
        __syncthreads();
        short8 a[MT], b[NT];
#pragma unroll
        for (int mt = 0; mt < MT; mt++) {
            int ml = wrow * WM + mt * 16 + lrow;
            a[mt] = *(const short8*)(As + ml * 32 + ko * 8);
        }
#pragma unroll
        for (int nt = 0; nt < NT; nt++) {
            int nl = wcol * WN + nt * 16 + lrow;
            b[nt] = *(const short8*)(Ws + nl * 32 + ko * 8);
        }
#pragma unroll
        for (int mt = 0; mt < MT; mt++)
#pragma unroll
            for (int nt = 0; nt < NT; nt++)
                acc[mt][nt] = __builtin_amdgcn_mfma_f32_16x16x32_bf16(
                    a[mt], b[nt], acc[mt][nt], 0, 0, 0);
        __syncthreads();
    }

    int r4 = lane >> 4;
#pragma unroll
    for (int mt = 0; mt < MT; mt++) {
#pragma unroll
        for (int nt = 0; nt < NT; nt++) {
            int n = n0 + wcol * WN + nt * 16 + lrow;
#pragma unroll
            for (int i = 0; i < 4; i++) {
                int m = m0 + wrow * WM + mt * 16 + r4 * 4 + i;
                float v = acc[mt][nt][i];
                size_t off = (size_t)m * N + n;
                if (EPI == 0) {
                    C[off] = v;
                } else if (EPI == 1) {
                    float t = v + bias[n];
                    Cb[off] = bf16_rn((t > 20.f) ? t : log1pf(expf(t)));
                } else if (EPI == 2) {
                    C[off] = v + res[off];
                } else if (EPI == 3) {
                    float t = v + bias[n];
                    Cb[off] = bf16_rn(0.5f * t * (1.f + erff(t * 0.70710678118654752f)));
                } else if (EPI == 4) {
                    C[off] = v + bias[n] + res[off];
                } else if (EPI == 5) {
                    C[off] = v;
                    if (n < DT_RANK) Cb[(size_t)m * DT_RANK + n] = bf16_rn(v);
                } else if (EPI == 6) {
                    Cb[off] = bf16_rn(v);
                }
            }
        }
    }
}

// ---------------------------------------------------------------------------
// Causal depthwise conv (width 4) + bias + SiLU. bf16 in (xz), bf16 out.
// ---------------------------------------------------------------------------
__global__ __launch_bounds__(256) void conv_silu_kernel(
    const ushort_t* __restrict__ xzb, const float* __restrict__ cw,
    const float* __restrict__ cb, ushort_t* __restrict__ xc_b) {
    int idx = blockIdx.x * 256 + threadIdx.x;  // 0 .. 4M-1
    int d = idx & (D_INNER - 1);
    int t = (idx >> 10) & (L_SEQ - 1);
    int b = idx >> 20;
    float acc = cb[d];
    const ushort_t* base = xzb + (size_t)(b * L_SEQ) * (2 * D_INNER) + d;
#pragma unroll
    for (int j = 0; j < 4; j++) {
        int tt = t - 3 + j;
        if (tt >= 0) acc += cw[d * 4 + j] * b2f(base[(size_t)tt * (2 * D_INNER)]);
    }
    float s = __fdividef(acc, 1.f + __expf(-acc));
    xc_b[idx] = bf16_rn(s);
}

// ---------------------------------------------------------------------------
// Chunked selective scan, d-per-lane: one lane per (b,chunk,d), 16 states in
// registers; B/C rows wave-uniform (scalar loads). dt/xc/z are bf16.
// ---------------------------------------------------------------------------
__global__ __launch_bounds__(256) void scan_pass1(
    const ushort_t* __restrict__ dt, const ushort_t* __restrict__ xc,
    const float* __restrict__ dbl, const float* __restrict__ A_log,
    float* __restrict__ Pbuf, float* __restrict__ Sbuf) {
    int tid = threadIdx.x;
    int blk = blockIdx.x;            // b*(NCHUNK*4) + c*4 + dg
    int dg = blk & 3;
    int c = (blk >> 2) & (NCHUNK - 1);
    int b = blk >> 7;
    int d = dg * 256 + tid;

    float A2[16], h[16], P[16];
    const float* ar = A_log + d * 16;
#pragma unroll
    for (int s = 0; s < 16; s++) {
        A2[s] = -__expf(ar[s]);
        h[s] = 0.f;
        P[s] = 1.f;
    }
    size_t rbase = (size_t)b * L_SEQ + (size_t)c * CHUNK;
    const ushort_t* dtp = dt + rbase * D_INNER + d;
    const ushort_t* xcp = xc + rbase * D_INNER + d;
    const float* blp = dbl + rbase * 64 + DT_RANK;   // B row (wave-uniform)

    float dtv = b2f(dtp[0]);
    float xcv = b2f(xcp[0]);
    float Ba[16], Bb[16];
#pragma unroll
    for (int s = 0; s < 16; s++) Ba[s] = blp[s];

    for (int t = 0; t < CHUNK; t += 2) {
        float dt1 = b2f(dtp[(size_t)(t + 1) * D_INNER]);
        float xc1 = b2f(xcp[(size_t)(t + 1) * D_INNER]);
#pragma unroll
        for (int s = 0; s < 16; s++) Bb[s] = blp[(t + 1) * 64 + s];
        {
            float u = dtv * xcv;
#pragma unroll
            for (int s = 0; s < 16; s++) {
                float a = __expf(dtv * A2[s]);
                h[s] = a * h[s] + u * Ba[s];
                P[s] *= a;
            }
        }
        float dt2 = 0.f, xc2 = 0.f;
        if (t + 2 < CHUNK) {
            dt2 = b2f(dtp[(size_t)(t + 2) * D_INNER]);
            xc2 = b2f(xcp[(size_t)(t + 2) * D_INNER]);
#pragma unroll
            for (int s = 0; s < 16; s++) Ba[s] = blp[(t + 2) * 64 + s];
        }
        {
            float u = dt1 * xc1;
#pragma unroll
            for (int s = 0; s < 16; s++) {
                float a = __expf(dt1 * A2[s]);
                h[s] = a * h[s] + u * Bb[s];
                P[s] *= a;
            }
        }
        dtv = dt2; xcv = xc2;
    }
    float* Pp = Pbuf + (((size_t)b * NCHUNK + c) * D_INNER + d) * 16;
    float* Sp = Sbuf + (((size_t)b * NCHUNK + c) * D_INNER + d) * 16;
#pragma unroll
    for (int q = 0; q < 4; q++) {
        *(float4*)(Pp + 4 * q) = make_float4(P[4 * q], P[4 * q + 1], P[4 * q + 2], P[4 * q + 3]);
        *(float4*)(Sp + 4 * q) = make_float4(h[4 * q], h[4 * q + 1], h[4 * q + 2], h[4 * q + 3]);
    }
}

// composes chunks; overwrites Pbuf[o] with Hin (incoming state) for chunk c.
__global__ __launch_bounds__(256) void scan_pass2(
    float* __restrict__ Pbuf, const float* __restrict__ Sbuf) {
    int idx = blockIdx.x * 256 + threadIdx.x;  // over B*D_INNER*D_STATE
    int sd = idx & 16383;
    int b = idx >> 14;
    float H = 0.f;
#pragma unroll
    for (int c = 0; c < NCHUNK; c++) {
        size_t o = ((size_t)(b * NCHUNK + c) << 14) + sd;
        float Pv = Pbuf[o];
        float Sv = Sbuf[o];
        Pbuf[o] = H;
        H = Pv * H + Sv;
    }
}

__global__ __launch_bounds__(256) void scan_pass3(
    const ushort_t* __restrict__ dt, const ushort_t* __restrict__ xc,
    const float* __restrict__ dbl, const ushort_t* __restrict__ xzb,
    const float* __restrict__ A_log, const float* __restrict__ Dsk,
    const float* __restrict__ Hin, ushort_t* __restrict__ y) {
    int tid = threadIdx.x;
    int blk = blockIdx.x;
    int dg = blk & 3;
    int c = (blk >> 2) & (NCHUNK - 1);
    int b = blk >> 7;
    int d = dg * 256 + tid;

    float A2[16], h[16];
    const float* ar = A_log + d * 16;
#pragma unroll
    for (int s = 0; s < 16; s++) A2[s] = -__expf(ar[s]);
    float Dv = Dsk[d];
    const float* Hp = Hin + (((size_t)b * NCHUNK + c) * D_INNER + d) * 16;
#pragma unroll
    for (int q = 0; q < 4; q++) {
        float4 hv = *(const float4*)(Hp + 4 * q);
        h[4 * q] = hv.x; h[4 * q + 1] = hv.y; h[4 * q + 2] = hv.z; h[4 * q + 3] = hv.w;
    }

    size_t rbase = (size_t)b * L_SEQ + (size_t)c * CHUNK;
    const ushort_t* dtp = dt + rbase * D_INNER + d;
    const ushort_t* xcp = xc + rbase * D_INNER + d;
    const float* blp = dbl + rbase * 64 + DT_RANK;   // [B(16) | C(16)] uniform
    const ushort_t* zp = xzb + rbase * (2 * D_INNER) + D_INNER + d;
    ushort_t* yp = y + rbase * D_INNER + d;

    float dtv = b2f(dtp[0]);
    float xcv = b2f(xcp[0]);
    float zv = b2f(zp[0]);
    float BCa[32], BCb[32];
#pragma unroll
    for (int s = 0; s < 32; s++) BCa[s] = blp[s];

    for (int t = 0; t < CHUNK; t += 2) {
        float dt1 = b2f(dtp[(size_t)(t + 1) * D_INNER]);
        float xc1 = b2f(xcp[(size_t)(t + 1) * D_INNER]);
        float z1 = b2f(zp[(size_t)(t + 1) * (2 * D_INNER)]);
#pragma unroll
        for (int s = 0; s < 32; s++) BCb[s] = blp[(t + 1) * 64 + s];
        {
            float u = dtv * xcv;
            float p = Dv * xcv;
#pragma unroll
            for (int s = 0; s < 16; s++) {
                float a = __expf(dtv * A2[s]);
                h[s] = a * h[s] + u * BCa[s];
                p = fmaf(h[s], BCa[16 + s], p);
            }
            float sig = __fdividef(zv, 1.f + __expf(-zv));
            yp[(size_t)t * D_INNER] = bf16_rn(p * sig);
        }
        float dt2 = 0.f, xc2 = 0.f, z2 = 0.f;
        if (t + 2 < CHUNK) {
            dt2 = b2f(dtp[(size_t)(t + 2) * D_INNER]);
            xc2 = b2f(xcp[(size_t)(t + 2) * D_INNER]);
            z2 = b2f(zp[(size_t)(t + 2) * (2 * D_INNER)]);
#pragma unroll
            for (int s = 0; s < 32; s++) BCa[s] = blp[(t + 2) * 64 + s];
        }
        {
            float u = dt1 * xc1;
            float p = Dv * xc1;
#pragma unroll
            for (int s = 0; s < 16; s++) {
                float a = __expf(dt1 * A2[s]);
                h[s] = a * h[s] + u * BCb[s];
                p = fmaf(h[s], BCb[16 + s], p);
            }
            float sig = __fdividef(z1, 1.f + __expf(-z1));
            yp[(size_t)(t + 1) * D_INNER] = bf16_rn(p * sig);
        }
        dtv = dt2; xcv = xc2; zv = z2;
    }
}

// ---------------------------------------------------------------------------
// Host launcher
// ---------------------------------------------------------------------------
extern "C" void kernel_launch(void* const* d_in, const int* in_sizes, int n_in,
                              void* d_out, int out_size, void* d_ws, size_t ws_size,
                              hipStream_t stream) {
    const float* x_in     = (const float*)d_in[0];
    const float* ln1_g    = (const float*)d_in[1];
    const float* ln1_b    = (const float*)d_in[2];
    const float* in_w     = (const float*)d_in[3];
    const float* conv_w   = (const float*)d_in[4];
    const float* conv_b   = (const float*)d_in[5];
    const float* xproj_w  = (const float*)d_in[6];
    const float* dtproj_w = (const float*)d_in[7];
    const float* dtproj_b = (const float*)d_in[8];
    const float* A_log    = (const float*)d_in[9];
    const float* D_skip   = (const float*)d_in[10];
    const float* out_w    = (const float*)d_in[11];
    const float* ln2_g    = (const float*)d_in[12];
    const float* ln2_b    = (const float*)d_in[13];
    const float* mlp_w1   = (const float*)d_in[14];
    const float* mlp_b1   = (const float*)d_in[15];
    const float* mlp_w2   = (const float*)d_in[16];
    const float* mlp_b2   = (const float*)d_in[17];

    char* p = (char*)d_ws;
    float* x_buf = (float*)p;        p += (size_t)NROWS * 512 * 4;            // 8 MB
    float* dbl   = (float*)p;        p += (size_t)NROWS * 64 * 4;             // 1 MB
    float* Pbuf  = (float*)p;        p += (size_t)BSZ * NCHUNK * 16384 * 4;   // 8 MB
    float* Sbuf  = (float*)p;        p += (size_t)BSZ * NCHUNK * 16384 * 4;   // 8 MB
    ushort_t* xz_b  = (ushort_t*)p;  p += (size_t)NROWS * 2048 * 2;           // 16 MB
    ushort_t* xn_b  = (ushort_t*)p;  p += (size_t)NROWS * 512 * 2;            // 4 MB
    ushort_t* xc_b  = (ushort_t*)p;  p += (size_t)NROWS * 1024 * 2;           // 8 MB
    ushort_t* dtr_b = (ushort_t*)p;  p += (size_t)NROWS * 32 * 2;
    ushort_t* dt_b  = (ushort_t*)p;  p += (size_t)NROWS * 1024 * 2;           // 8 MB
    ushort_t* yc_b  = (ushort_t*)p;  p += (size_t)NROWS * 1024 * 2;           // 8 MB
    ushort_t* wall  = (ushort_t*)p;  // contiguous weight block (order matters!)
    ushort_t* wi_b  = wall;                       // 5*2048*512
    ushort_t* wx_b  = wall + 5242880;             // 5*64*1024
    ushort_t* wd_b  = wall + 5570560;             // 5*1024*32
    ushort_t* wo_b  = wall + 5734400;             // 5*512*1024
    ushort_t* w1_b  = wall + 8355840;             // 5*1024*512
    ushort_t* w2_b  = wall + 10977280;            // 5*512*1024
    ushort_t* h1_b  = xz_b;  // alias: xz dead once mlp1 runs

    // all weights fp32 -> bf16, one dispatch
    f2b_all_kernel<<<(F2B_TOT + 255) / 256, 256, 0, stream>>>(
        in_w, xproj_w, dtproj_w, out_w, mlp_w1, mlp_w2, wall);

    for (int d = 0; d < 5; d++) {
        const float* xsrc = (d == 0) ? x_in : x_buf;

        // LN1 -> bf16
        ln_kernel<<<NROWS, 64, 0, stream>>>(xsrc, ln1_g + d * 512, ln1_b + d * 512, xn_b);
        // in_proj: 4096x2048, K=512 -> bf16 xz
        bgemm_kernel<128, 128, 6><<<dim3(16, 32), 256, 0, stream>>>(
            xn_b, wi_b + (size_t)d * 2048 * 512, nullptr, nullptr, nullptr, xz_b,
            NROWS, 2048, 512);
        // conv + silu -> bf16 xc
        conv_silu_kernel<<<(NROWS * D_INNER) / 256, 256, 0, stream>>>(
            xz_b, conv_w + d * 4096, conv_b + d * 1024, xc_b);
        // xproj: 4096x64, K=1024 -> dbl fp32 + dtr bf16 (32x64 tile, 128 blocks)
        bgemm_kernel<32, 64, 5><<<dim3(1, 128), 256, 0, stream>>>(
            xc_b, wx_b + (size_t)d * 64 * 1024, nullptr, nullptr, dbl, dtr_b,
            NROWS, 64, 1024);
        // dtproj + softplus: 4096x1024, K=32 -> bf16 dt
        bgemm_kernel<128, 128, 1><<<dim3(8, 32), 256, 0, stream>>>(
            dtr_b, wd_b + (size_t)d * 1024 * 32, dtproj_b + d * 1024, nullptr, nullptr, dt_b,
            NROWS, 1024, 32);
        // chunked scan (d-per-lane)
        scan_pass1<<<BSZ * NCHUNK * 4, 256, 0, stream>>>(
            dt_b, xc_b, dbl, A_log + d * 16384, Pbuf, Sbuf);
        scan_pass2<<<(BSZ * D_INNER * D_STATE) / 256, 256, 0, stream>>>(Pbuf, Sbuf);
        scan_pass3<<<BSZ * NCHUNK * 4, 256, 0, stream>>>(
            dt_b, xc_b, dbl, xz_b, A_log + d * 16384, D_skip + d * 1024, Pbuf, yc_b);
        // out_proj + residual: 4096x512, K=1024 -> fp32 x_buf
        bgemm_kernel<128, 64, 2><<<dim3(8, 32), 256, 0, stream>>>(
            yc_b, wo_b + (size_t)d * 512 * 1024, nullptr, xsrc, x_buf, nullptr,
            NROWS, 512, 1024);
        // LN2 -> bf16
        ln_kernel<<<NROWS, 64, 0, stream>>>(x_buf, ln2_g + d * 512, ln2_b + d * 512, xn_b);
        // mlp1 + bias + gelu -> bf16 h1: 4096x1024, K=512
        bgemm_kernel<128, 128, 3><<<dim3(8, 32), 256, 0, stream>>>(
            xn_b, w1_b + (size_t)d * 1024 * 512, mlp_b1 + d * 1024, nullptr, nullptr, h1_b,
            NROWS, 1024, 512);
        // mlp2 + bias + residual: 4096x512, K=1024
        float* dst = (d == 4) ? (float*)d_out : x_buf;
        bgemm_kernel<128, 64, 4><<<dim3(8, 32), 256, 0, stream>>>(
            h1_b, w2_b + (size_t)d * 512 * 1024, mlp_b2 + d * 512, x_buf, dst, nullptr,
            NROWS, 512, 1024);
    }
}

// Round 6
// 1263.916 us; speedup vs baseline: 1.4130x; 1.4130x over previous
//
#include <hip/hip_runtime.h>
#include <math.h>

#define D_MODEL 512
#define D_INNER 1024
#define L_SEQ 1024
#define BSZ 4
#define NROWS (BSZ * L_SEQ) /* 4096 */
#define DT_RANK 32
#define D_STATE 16
#define CHUNK 32
#define NCHUNK (L_SEQ / CHUNK) /* 32 */

typedef unsigned short ushort_t;
typedef __attribute__((ext_vector_type(8))) short short8;
typedef __attribute__((ext_vector_type(4))) float f32x4;

__device__ inline ushort_t bf16_rn(float f) {
    union { float f; unsigned u; } v; v.f = f;
    unsigned r = v.u + 0x7fffu + ((v.u >> 16) & 1u);
    return (ushort_t)(r >> 16);
}
__device__ inline float b2f(ushort_t u) {
    union { unsigned u; float f; } v; v.u = (unsigned)u << 16; return v.f;
}

// ---------------------------------------------------------------------------
// Five weight tensors fp32 -> bf16 in ONE dispatch (dtproj_w stays fp32).
// Order in wall: in_w, xproj_w, out_w, mlp_w1, mlp_w2 (uint2 idx == i).
// ---------------------------------------------------------------------------
#define F2B_TOT 3358720  /* total float4 groups across the 5 tensors */
__global__ __launch_bounds__(256) void f2b_all_kernel(
    const float* __restrict__ w0, const float* __restrict__ w1,
    const float* __restrict__ w2, const float* __restrict__ w3,
    const float* __restrict__ w4, ushort_t* __restrict__ dst) {
    int i = blockIdx.x * 256 + threadIdx.x;
    if (i >= F2B_TOT) return;
    const float* src; int j;
    if (i < 1310720)      { src = w0; j = i; }
    else if (i < 1392640) { src = w1; j = i - 1310720; }
    else if (i < 2048000) { src = w2; j = i - 1392640; }
    else if (i < 2703360) { src = w3; j = i - 2048000; }
    else                  { src = w4; j = i - 2703360; }
    float4 v = ((const float4*)src)[j];
    uint2 pk;
    pk.x = (unsigned)bf16_rn(v.x) | ((unsigned)bf16_rn(v.y) << 16);
    pk.y = (unsigned)bf16_rn(v.z) | ((unsigned)bf16_rn(v.w) << 16);
    ((uint2*)dst)[i] = pk;
}

// ---------------------------------------------------------------------------
// LayerNorm: one wave per row of 512, bf16 output (feeds a GEMM)
// ---------------------------------------------------------------------------
__global__ __launch_bounds__(64) void ln_kernel(const float* __restrict__ x,
                                                const float* __restrict__ g,
                                                const float* __restrict__ b,
                                                ushort_t* __restrict__ out) {
    int row = blockIdx.x;
    int lane = threadIdx.x;
    const float* xr = x + (size_t)row * D_MODEL;
    float4 v0 = *(const float4*)(xr + lane * 8);
    float4 v1 = *(const float4*)(xr + lane * 8 + 4);
    float s = v0.x + v0.y + v0.z + v0.w + v1.x + v1.y + v1.z + v1.w;
    float ss = v0.x * v0.x + v0.y * v0.y + v0.z * v0.z + v0.w * v0.w +
               v1.x * v1.x + v1.y * v1.y + v1.z * v1.z + v1.w * v1.w;
#pragma unroll
    for (int o = 32; o >= 1; o >>= 1) {
        s += __shfl_xor(s, o);
        ss += __shfl_xor(ss, o);
    }
    float mean = s * (1.f / D_MODEL);
    float var = ss * (1.f / D_MODEL) - mean * mean;
    float rstd = rsqrtf(var + 1e-5f);
    float4 g0 = *(const float4*)(g + lane * 8);
    float4 g1 = *(const float4*)(g + lane * 8 + 4);
    float4 b0 = *(const float4*)(b + lane * 8);
    float4 b1 = *(const float4*)(b + lane * 8 + 4);
    float o0 = (v0.x - mean) * rstd * g0.x + b0.x;
    float o1 = (v0.y - mean) * rstd * g0.y + b0.y;
    float o2 = (v0.z - mean) * rstd * g0.z + b0.z;
    float o3 = (v0.w - mean) * rstd * g0.w + b0.w;
    float o4 = (v1.x - mean) * rstd * g1.x + b1.x;
    float o5 = (v1.y - mean) * rstd * g1.y + b1.y;
    float o6 = (v1.z - mean) * rstd * g1.z + b1.z;
    float o7 = (v1.w - mean) * rstd * g1.w + b1.w;
    uint4 pk;
    pk.x = (unsigned)bf16_rn(o0) | ((unsigned)bf16_rn(o1) << 16);
    pk.y = (unsigned)bf16_rn(o2) | ((unsigned)bf16_rn(o3) << 16);
    pk.z = (unsigned)bf16_rn(o4) | ((unsigned)bf16_rn(o5) << 16);
    pk.w = (unsigned)bf16_rn(o6) | ((unsigned)bf16_rn(o7) << 16);
    *(uint4*)(out + (size_t)row * D_MODEL + lane * 8) = pk;
}

// ---------------------------------------------------------------------------
// bf16 MFMA GEMM: C[m,n] = epi( sum_k A[m,k]*W[n,k] ), fp32 accumulate.
// EPI: 0 fp32   2 +res fp32   3 bias+gelu -> bf16   4 bias+res fp32
//      6 plain bf16
// ---------------------------------------------------------------------------
template <int BMt, int BNt, int EPI>
__global__ __launch_bounds__(256) void bgemm_kernel(
    const ushort_t* __restrict__ A, const ushort_t* __restrict__ W,
    const float* __restrict__ bias, const float* __restrict__ res,
    float* __restrict__ C, ushort_t* __restrict__ Cb,
    int M, int N, int K) {
    constexpr int WM = BMt / 2, WN = BNt / 2;
    constexpr int MT = WM / 16, NT = WN / 16;
    constexpr int ACH = BMt * 4;            // 16B chunks in A tile
    constexpr int TOT = ACH + BNt * 4;
    __shared__ ushort_t As[BMt * 32];
    __shared__ ushort_t Ws[BNt * 32];

    int tid = threadIdx.x;
    int lane = tid & 63;
    int wv = tid >> 6;
    int wrow = wv >> 1, wcol = wv & 1;
    int m0 = blockIdx.y * BMt, n0 = blockIdx.x * BNt;
    int lrow = lane & 15;
    int ko = lane >> 4;

    f32x4 acc[MT][NT] = {};

    for (int k0 = 0; k0 < K; k0 += 32) {
#pragma unroll
        for (int i = 0; i < (TOT + 255) / 256; i++) {
            int e = tid + i * 256;
            if (e < TOT) {
                const ushort_t* gp;
                ushort_t* lp;
                if (e < ACH) {
                    int row = e >> 2, ch = e & 3;
                    gp = A + (size_t)(m0 + row) * K + k0 + ch * 8;
                    lp = As + e * 8;
                } else {
                    int e2 = e - ACH;
                    int row = e2 >> 2, ch = e2 & 3;
                    gp = W + (size_t)(n0 + row) * K + k0 + ch * 8;
                    lp = Ws + e2 * 8;
                }
                __builtin_amdgcn_global_load_lds(
                    (const __attribute__((address_space(1))) void*)gp,
                    (__attribute__((address_space(3))) void*)lp, 16, 0, 0);
            }
        }
        __syncthreads();
        short8 a[MT], b[NT];
#pragma unroll
        for (int mt = 0; mt < MT; mt++) {
            int ml = wrow * WM + mt * 16 + lrow;
            a[mt] = *(const short8*)(As + ml * 32 + ko * 8);
        }
#pragma unroll
        for (int nt = 0; nt < NT; nt++) {
            int nl = wcol * WN + nt * 16 + lrow;
            b[nt] = *(const short8*)(Ws + nl * 32 + ko * 8);
        }
#pragma unroll
        for (int mt = 0; mt < MT; mt++)
#pragma unroll
            for (int nt = 0; nt < NT; nt++)
                acc[mt][nt] = __builtin_amdgcn_mfma_f32_16x16x32_bf16(
                    a[mt], b[nt], acc[mt][nt], 0, 0, 0);
        __syncthreads();
    }

    int r4 = lane >> 4;
#pragma unroll
    for (int mt = 0; mt < MT; mt++) {
#pragma unroll
        for (int nt = 0; nt < NT; nt++) {
            int n = n0 + wcol * WN + nt * 16 + lrow;
#pragma unroll
            for (int i = 0; i < 4; i++) {
                int m = m0 + wrow * WM + mt * 16 + r4 * 4 + i;
                float v = acc[mt][nt][i];
                size_t off = (size_t)m * N + n;
                if (EPI == 0) {
                    C[off] = v;
                } else if (EPI == 2) {
                    C[off] = v + res[off];
                } else if (EPI == 3) {
                    float t = v + bias[n];
                    Cb[off] = bf16_rn(0.5f * t * (1.f + erff(t * 0.70710678118654752f)));
                } else if (EPI == 4) {
                    C[off] = v + bias[n] + res[off];
                } else if (EPI == 6) {
                    Cb[off] = bf16_rn(v);
                }
            }
        }
    }
}

// ---------------------------------------------------------------------------
// dtproj + softplus as fp32 VALU kernel (268 MFLOP — MFMA is the wrong tool;
// the K=32 bgemm version was 100% epilogue and pathologically slow).
// Block: 16 rows x 1024 cols. dtr slice of dbl staged in LDS (broadcast
// reads); wd row per thread in registers; coalesced bf16 stores.
// ---------------------------------------------------------------------------
__global__ __launch_bounds__(256) void dt_kernel(
    const float* __restrict__ dbl, const float* __restrict__ wd,
    const float* __restrict__ bias, ushort_t* __restrict__ dt_b) {
    int m0 = blockIdx.x * 16;
    int tid = threadIdx.x;
    __shared__ float dtr[16][32];
    if (tid < 128) {
        int r = tid >> 3, q = tid & 7;
        *(float4*)&dtr[r][q * 4] = *(const float4*)(dbl + (size_t)(m0 + r) * 64 + q * 4);
    }
    __syncthreads();
#pragma unroll
    for (int cg = 0; cg < 4; cg++) {
        int n = cg * 256 + tid;
        float w[32];
#pragma unroll
        for (int q = 0; q < 8; q++) {
            float4 v = *(const float4*)(wd + (size_t)n * 32 + q * 4);
            w[q * 4 + 0] = v.x; w[q * 4 + 1] = v.y;
            w[q * 4 + 2] = v.z; w[q * 4 + 3] = v.w;
        }
        float bn = bias[n];
        float acc[16];
#pragma unroll
        for (int r = 0; r < 16; r++) acc[r] = bn;
#pragma unroll
        for (int k = 0; k < 32; k++) {
            float wk = w[k];
#pragma unroll
            for (int r = 0; r < 16; r++) acc[r] = fmaf(dtr[r][k], wk, acc[r]);
        }
#pragma unroll
        for (int r = 0; r < 16; r++) {
            float t = acc[r];
            float sp = (t > 20.f) ? t : log1pf(__expf(t));
            dt_b[(size_t)(m0 + r) * D_INNER + n] = bf16_rn(sp);
        }
    }
}

// ---------------------------------------------------------------------------
// Causal depthwise conv (width 4) + bias + SiLU. bf16 in (xz), bf16 out.
// ---------------------------------------------------------------------------
__global__ __launch_bounds__(256) void conv_silu_kernel(
    const ushort_t* __restrict__ xzb, const float* __restrict__ cw,
    const float* __restrict__ cb, ushort_t* __restrict__ xc_b) {
    int idx = blockIdx.x * 256 + threadIdx.x;  // 0 .. 4M-1
    int d = idx & (D_INNER - 1);
    int t = (idx >> 10) & (L_SEQ - 1);
    int b = idx >> 20;
    float acc = cb[d];
    const ushort_t* base = xzb + (size_t)(b * L_SEQ) * (2 * D_INNER) + d;
#pragma unroll
    for (int j = 0; j < 4; j++) {
        int tt = t - 3 + j;
        if (tt >= 0) acc += cw[d * 4 + j] * b2f(base[(size_t)tt * (2 * D_INNER)]);
    }
    float s = __fdividef(acc, 1.f + __expf(-acc));
    xc_b[idx] = bf16_rn(s);
}

// ---------------------------------------------------------------------------
// Chunked selective scan, d-per-lane: one lane per (b,chunk,d), 16 states in
// registers; B/C rows wave-uniform (scalar loads). dt/xc/z are bf16.
// ---------------------------------------------------------------------------
__global__ __launch_bounds__(256) void scan_pass1(
    const ushort_t* __restrict__ dt, const ushort_t* __restrict__ xc,
    const float* __restrict__ dbl, const float* __restrict__ A_log,
    float* __restrict__ Pbuf, float* __restrict__ Sbuf) {
    int tid = threadIdx.x;
    int blk = blockIdx.x;            // b*(NCHUNK*4) + c*4 + dg
    int dg = blk & 3;
    int c = (blk >> 2) & (NCHUNK - 1);
    int b = blk >> 7;
    int d = dg * 256 + tid;

    float A2[16], h[16], P[16];
    const float* ar = A_log + d * 16;
#pragma unroll
    for (int s = 0; s < 16; s++) {
        A2[s] = -__expf(ar[s]);
        h[s] = 0.f;
        P[s] = 1.f;
    }
    size_t rbase = (size_t)b * L_SEQ + (size_t)c * CHUNK;
    const ushort_t* dtp = dt + rbase * D_INNER + d;
    const ushort_t* xcp = xc + rbase * D_INNER + d;
    const float* blp = dbl + rbase * 64 + DT_RANK;   // B row (wave-uniform)

    float dtv = b2f(dtp[0]);
    float xcv = b2f(xcp[0]);
    float Ba[16], Bb[16];
#pragma unroll
    for (int s = 0; s < 16; s++) Ba[s] = blp[s];

    for (int t = 0; t < CHUNK; t += 2) {
        float dt1 = b2f(dtp[(size_t)(t + 1) * D_INNER]);
        float xc1 = b2f(xcp[(size_t)(t + 1) * D_INNER]);
#pragma unroll
        for (int s = 0; s < 16; s++) Bb[s] = blp[(t + 1) * 64 + s];
        {
            float u = dtv * xcv;
#pragma unroll
            for (int s = 0; s < 16; s++) {
                float a = __expf(dtv * A2[s]);
                h[s] = a * h[s] + u * Ba[s];
                P[s] *= a;
            }
        }
        float dt2 = 0.f, xc2 = 0.f;
        if (t + 2 < CHUNK) {
            dt2 = b2f(dtp[(size_t)(t + 2) * D_INNER]);
            xc2 = b2f(xcp[(size_t)(t + 2) * D_INNER]);
#pragma unroll
            for (int s = 0; s < 16; s++) Ba[s] = blp[(t + 2) * 64 + s];
        }
        {
            float u = dt1 * xc1;
#pragma unroll
            for (int s = 0; s < 16; s++) {
                float a = __expf(dt1 * A2[s]);
                h[s] = a * h[s] + u * Bb[s];
                P[s] *= a;
            }
        }
        dtv = dt2; xcv = xc2;
    }
    float* Pp = Pbuf + (((size_t)b * NCHUNK + c) * D_INNER + d) * 16;
    float* Sp = Sbuf + (((size_t)b * NCHUNK + c) * D_INNER + d) * 16;
#pragma unroll
    for (int q = 0; q < 4; q++) {
        *(float4*)(Pp + 4 * q) = make_float4(P[4 * q], P[4 * q + 1], P[4 * q + 2], P[4 * q + 3]);
        *(float4*)(Sp + 4 * q) = make_float4(h[4 * q], h[4 * q + 1], h[4 * q + 2], h[4 * q + 3]);
    }
}

// composes chunks; overwrites Pbuf[o] with Hin (incoming state) for chunk c.
__global__ __launch_bounds__(256) void scan_pass2(
    float* __restrict__ Pbuf, const float* __restrict__ Sbuf) {
    int idx = blockIdx.x * 256 + threadIdx.x;  // over B*D_INNER*D_STATE
    int sd = idx & 16383;
    int b = idx >> 14;
    float H = 0.f;
#pragma unroll
    for (int c = 0; c < NCHUNK; c++) {
        size_t o = ((size_t)(b * NCHUNK + c) << 14) + sd;
        float Pv = Pbuf[o];
        float Sv = Sbuf[o];
        Pbuf[o] = H;
        H = Pv * H + Sv;
    }
}

__global__ __launch_bounds__(256) void scan_pass3(
    const ushort_t* __restrict__ dt, const ushort_t* __restrict__ xc,
    const float* __restrict__ dbl, const ushort_t* __restrict__ xzb,
    const float* __restrict__ A_log, const float* __restrict__ Dsk,
    const float* __restrict__ Hin, ushort_t* __restrict__ y) {
    int tid = threadIdx.x;
    int blk = blockIdx.x;
    int dg = blk & 3;
    int c = (blk >> 2) & (NCHUNK - 1);
    int b = blk >> 7;
    int d = dg * 256 + tid;

    float A2[16], h[16];
    const float* ar = A_log + d * 16;
#pragma unroll
    for (int s = 0; s < 16; s++) A2[s] = -__expf(ar[s]);
    float Dv = Dsk[d];
    const float* Hp = Hin + (((size_t)b * NCHUNK + c) * D_INNER + d) * 16;
#pragma unroll
    for (int q = 0; q < 4; q++) {
        float4 hv = *(const float4*)(Hp + 4 * q);
        h[4 * q] = hv.x; h[4 * q + 1] = hv.y; h[4 * q + 2] = hv.z; h[4 * q + 3] = hv.w;
    }

    size_t rbase = (size_t)b * L_SEQ + (size_t)c * CHUNK;
    const ushort_t* dtp = dt + rbase * D_INNER + d;
    const ushort_t* xcp = xc + rbase * D_INNER + d;
    const float* blp = dbl + rbase * 64 + DT_RANK;   // [B(16) | C(16)] uniform
    const ushort_t* zp = xzb + rbase * (2 * D_INNER) + D_INNER + d;
    ushort_t* yp = y + rbase * D_INNER + d;

    float dtv = b2f(dtp[0]);
    float xcv = b2f(xcp[0]);
    float zv = b2f(zp[0]);
    float BCa[32], BCb[32];
#pragma unroll
    for (int s = 0; s < 32; s++) BCa[s] = blp[s];

    for (int t = 0; t < CHUNK; t += 2) {
        float dt1 = b2f(dtp[(size_t)(t + 1) * D_INNER]);
        float xc1 = b2f(xcp[(size_t)(t + 1) * D_INNER]);
        float z1 = b2f(zp[(size_t)(t + 1) * (2 * D_INNER)]);
#pragma unroll
        for (int s = 0; s < 32; s++) BCb[s] = blp[(t + 1) * 64 + s];
        {
            float u = dtv * xcv;
            float p = Dv * xcv;
#pragma unroll
            for (int s = 0; s < 16; s++) {
                float a = __expf(dtv * A2[s]);
                h[s] = a * h[s] + u * BCa[s];
                p = fmaf(h[s], BCa[16 + s], p);
            }
            float sig = __fdividef(zv, 1.f + __expf(-zv));
            yp[(size_t)t * D_INNER] = bf16_rn(p * sig);
        }
        float dt2 = 0.f, xc2 = 0.f, z2 = 0.f;
        if (t + 2 < CHUNK) {
            dt2 = b2f(dtp[(size_t)(t + 2) * D_INNER]);
            xc2 = b2f(xcp[(size_t)(t + 2) * D_INNER]);
            z2 = b2f(zp[(size_t)(t + 2) * (2 * D_INNER)]);
#pragma unroll
            for (int s = 0; s < 32; s++) BCa[s] = blp[(t + 2) * 64 + s];
        }
        {
            float u = dt1 * xc1;
            float p = Dv * xc1;
#pragma unroll
            for (int s = 0; s < 16; s++) {
                float a = __expf(dt1 * A2[s]);
                h[s] = a * h[s] + u * BCb[s];
                p = fmaf(h[s], BCb[16 + s], p);
            }
            float sig = __fdividef(z1, 1.f + __expf(-z1));
            yp[(size_t)(t + 1) * D_INNER] = bf16_rn(p * sig);
        }
        dtv = dt2; xcv = xc2; zv = z2;
    }
}

// ---------------------------------------------------------------------------
// Host launcher
// ---------------------------------------------------------------------------
extern "C" void kernel_launch(void* const* d_in, const int* in_sizes, int n_in,
                              void* d_out, int out_size, void* d_ws, size_t ws_size,
                              hipStream_t stream) {
    const float* x_in     = (const float*)d_in[0];
    const float* ln1_g    = (const float*)d_in[1];
    const float* ln1_b    = (const float*)d_in[2];
    const float* in_w     = (const float*)d_in[3];
    const float* conv_w   = (const float*)d_in[4];
    const float* conv_b   = (const float*)d_in[5];
    const float* xproj_w  = (const float*)d_in[6];
    const float* dtproj_w = (const float*)d_in[7];
    const float* dtproj_b = (const float*)d_in[8];
    const float* A_log    = (const float*)d_in[9];
    const float* D_skip   = (const float*)d_in[10];
    const float* out_w    = (const float*)d_in[11];
    const float* ln2_g    = (const float*)d_in[12];
    const float* ln2_b    = (const float*)d_in[13];
    const float* mlp_w1   = (const float*)d_in[14];
    const float* mlp_b1   = (const float*)d_in[15];
    const float* mlp_w2   = (const float*)d_in[16];
    const float* mlp_b2   = (const float*)d_in[17];

    char* p = (char*)d_ws;
    float* x_buf = (float*)p;        p += (size_t)NROWS * 512 * 4;            // 8 MB
    float* dbl   = (float*)p;        p += (size_t)NROWS * 64 * 4;             // 1 MB
    float* Pbuf  = (float*)p;        p += (size_t)BSZ * NCHUNK * 16384 * 4;   // 8 MB
    float* Sbuf  = (float*)p;        p += (size_t)BSZ * NCHUNK * 16384 * 4;   // 8 MB
    ushort_t* xz_b  = (ushort_t*)p;  p += (size_t)NROWS * 2048 * 2;           // 16 MB
    ushort_t* xn_b  = (ushort_t*)p;  p += (size_t)NROWS * 512 * 2;            // 4 MB
    ushort_t* xc_b  = (ushort_t*)p;  p += (size_t)NROWS * 1024 * 2;           // 8 MB
    ushort_t* dt_b  = (ushort_t*)p;  p += (size_t)NROWS * 1024 * 2;           // 8 MB
    ushort_t* yc_b  = (ushort_t*)p;  p += (size_t)NROWS * 1024 * 2;           // 8 MB
    ushort_t* wall  = (ushort_t*)p;  // contiguous weight block (order matters!)
    ushort_t* wi_b  = wall;                       // 5*2048*512
    ushort_t* wx_b  = wall + 5242880;             // 5*64*1024
    ushort_t* wo_b  = wall + 5570560;             // 5*512*1024
    ushort_t* w1_b  = wall + 8192000;             // 5*1024*512
    ushort_t* w2_b  = wall + 10813440;            // 5*512*1024
    ushort_t* h1_b  = xz_b;  // alias: xz dead once mlp1 runs

    // weights fp32 -> bf16, one dispatch (dtproj_w stays fp32)
    f2b_all_kernel<<<(F2B_TOT + 255) / 256, 256, 0, stream>>>(
        in_w, xproj_w, out_w, mlp_w1, mlp_w2, wall);

    for (int d = 0; d < 5; d++) {
        const float* xsrc = (d == 0) ? x_in : x_buf;

        // LN1 -> bf16
        ln_kernel<<<NROWS, 64, 0, stream>>>(xsrc, ln1_g + d * 512, ln1_b + d * 512, xn_b);
        // in_proj: 4096x2048, K=512 -> bf16 xz
        bgemm_kernel<128, 128, 6><<<dim3(16, 32), 256, 0, stream>>>(
            xn_b, wi_b + (size_t)d * 2048 * 512, nullptr, nullptr, nullptr, xz_b,
            NROWS, 2048, 512);
        // conv + silu -> bf16 xc
        conv_silu_kernel<<<(NROWS * D_INNER) / 256, 256, 0, stream>>>(
            xz_b, conv_w + d * 4096, conv_b + d * 1024, xc_b);
        // xproj: 4096x64, K=1024 -> fp32 dbl
        bgemm_kernel<32, 64, 0><<<dim3(1, 128), 256, 0, stream>>>(
            xc_b, wx_b + (size_t)d * 64 * 1024, nullptr, nullptr, dbl, nullptr,
            NROWS, 64, 1024);
        // dtproj + softplus (fp32 VALU, coalesced bf16 out)
        dt_kernel<<<NROWS / 16, 256, 0, stream>>>(
            dbl, dtproj_w + (size_t)d * 1024 * 32, dtproj_b + d * 1024, dt_b);
        // chunked scan (d-per-lane)
        scan_pass1<<<BSZ * NCHUNK * 4, 256, 0, stream>>>(
            dt_b, xc_b, dbl, A_log + d * 16384, Pbuf, Sbuf);
        scan_pass2<<<(BSZ * D_INNER * D_STATE) / 256, 256, 0, stream>>>(Pbuf, Sbuf);
        scan_pass3<<<BSZ * NCHUNK * 4, 256, 0, stream>>>(
            dt_b, xc_b, dbl, xz_b, A_log + d * 16384, D_skip + d * 1024, Pbuf, yc_b);
        // out_proj + residual: 4096x512, K=1024 -> fp32 x_buf
        bgemm_kernel<128, 64, 2><<<dim3(8, 32), 256, 0, stream>>>(
            yc_b, wo_b + (size_t)d * 512 * 1024, nullptr, xsrc, x_buf, nullptr,
            NROWS, 512, 1024);
        // LN2 -> bf16
        ln_kernel<<<NROWS, 64, 0, stream>>>(x_buf, ln2_g + d * 512, ln2_b + d * 512, xn_b);
        // mlp1 + bias + gelu -> bf16 h1: 4096x1024, K=512
        bgemm_kernel<128, 128, 3><<<dim3(8, 32), 256, 0, stream>>>(
            xn_b, w1_b + (size_t)d * 1024 * 512, mlp_b1 + d * 1024, nullptr, nullptr, h1_b,
            NROWS, 1024, 512);
        // mlp2 + bias + residual: 4096x512, K=1024
        float* dst = (d == 4) ? (float*)d_out : x_buf;
        bgemm_kernel<128, 64, 4><<<dim3(8, 32), 256, 0, stream>>>(
            h1_b, w2_b + (size_t)d * 512 * 1024, mlp_b2 + d * 512, x_buf, dst, nullptr,
            NROWS, 512, 1024);
    }
}

// Round 7
// 1179.114 us; speedup vs baseline: 1.5147x; 1.0719x over previous
//
#include <hip/hip_runtime.h>
#include <math.h>

#define D_MODEL 512
#define D_INNER 1024
#define L_SEQ 1024
#define BSZ 4
#define NROWS (BSZ * L_SEQ) /* 4096 */
#define DT_RANK 32
#define D_STATE 16
#define CHUNK 32
#define NCHUNK (L_SEQ / CHUNK) /* 32 */

typedef unsigned short ushort_t;
typedef __attribute__((ext_vector_type(8))) short short8;
typedef __attribute__((ext_vector_type(4))) float f32x4;

__device__ inline ushort_t bf16_rn(float f) {
    union { float f; unsigned u; } v; v.f = f;
    unsigned r = v.u + 0x7fffu + ((v.u >> 16) & 1u);
    return (ushort_t)(r >> 16);
}
__device__ inline float b2f(ushort_t u) {
    union { unsigned u; float f; } v; v.u = (unsigned)u << 16; return v.f;
}

// ---------------------------------------------------------------------------
// Five weight tensors fp32 -> bf16 in ONE dispatch (dtproj_w stays fp32).
// Order in wall: in_w, xproj_w, out_w, mlp_w1, mlp_w2 (uint2 idx == i).
// ---------------------------------------------------------------------------
#define F2B_TOT 3358720  /* total float4 groups across the 5 tensors */
__global__ __launch_bounds__(256) void f2b_all_kernel(
    const float* __restrict__ w0, const float* __restrict__ w1,
    const float* __restrict__ w2, const float* __restrict__ w3,
    const float* __restrict__ w4, ushort_t* __restrict__ dst) {
    int i = blockIdx.x * 256 + threadIdx.x;
    if (i >= F2B_TOT) return;
    const float* src; int j;
    if (i < 1310720)      { src = w0; j = i; }
    else if (i < 1392640) { src = w1; j = i - 1310720; }
    else if (i < 2048000) { src = w2; j = i - 1392640; }
    else if (i < 2703360) { src = w3; j = i - 2048000; }
    else                  { src = w4; j = i - 2703360; }
    float4 v = ((const float4*)src)[j];
    uint2 pk;
    pk.x = (unsigned)bf16_rn(v.x) | ((unsigned)bf16_rn(v.y) << 16);
    pk.y = (unsigned)bf16_rn(v.z) | ((unsigned)bf16_rn(v.w) << 16);
    ((uint2*)dst)[i] = pk;
}

// ---------------------------------------------------------------------------
// LayerNorm: one wave per row of 512, bf16 output (feeds a GEMM)
// ---------------------------------------------------------------------------
__global__ __launch_bounds__(64) void ln_kernel(const float* __restrict__ x,
                                                const float* __restrict__ g,
                                                const float* __restrict__ b,
                                                ushort_t* __restrict__ out) {
    int row = blockIdx.x;
    int lane = threadIdx.x;
    const float* xr = x + (size_t)row * D_MODEL;
    float4 v0 = *(const float4*)(xr + lane * 8);
    float4 v1 = *(const float4*)(xr + lane * 8 + 4);
    float s = v0.x + v0.y + v0.z + v0.w + v1.x + v1.y + v1.z + v1.w;
    float ss = v0.x * v0.x + v0.y * v0.y + v0.z * v0.z + v0.w * v0.w +
               v1.x * v1.x + v1.y * v1.y + v1.z * v1.z + v1.w * v1.w;
#pragma unroll
    for (int o = 32; o >= 1; o >>= 1) {
        s += __shfl_xor(s, o);
        ss += __shfl_xor(ss, o);
    }
    float mean = s * (1.f / D_MODEL);
    float var = ss * (1.f / D_MODEL) - mean * mean;
    float rstd = rsqrtf(var + 1e-5f);
    float4 g0 = *(const float4*)(g + lane * 8);
    float4 g1 = *(const float4*)(g + lane * 8 + 4);
    float4 b0 = *(const float4*)(b + lane * 8);
    float4 b1 = *(const float4*)(b + lane * 8 + 4);
    float o0 = (v0.x - mean) * rstd * g0.x + b0.x;
    float o1 = (v0.y - mean) * rstd * g0.y + b0.y;
    float o2 = (v0.z - mean) * rstd * g0.z + b0.z;
    float o3 = (v0.w - mean) * rstd * g0.w + b0.w;
    float o4 = (v1.x - mean) * rstd * g1.x + b1.x;
    float o5 = (v1.y - mean) * rstd * g1.y + b1.y;
    float o6 = (v1.z - mean) * rstd * g1.z + b1.z;
    float o7 = (v1.w - mean) * rstd * g1.w + b1.w;
    uint4 pk;
    pk.x = (unsigned)bf16_rn(o0) | ((unsigned)bf16_rn(o1) << 16);
    pk.y = (unsigned)bf16_rn(o2) | ((unsigned)bf16_rn(o3) << 16);
    pk.z = (unsigned)bf16_rn(o4) | ((unsigned)bf16_rn(o5) << 16);
    pk.w = (unsigned)bf16_rn(o6) | ((unsigned)bf16_rn(o7) << 16);
    *(uint4*)(out + (size_t)row * D_MODEL + lane * 8) = pk;
}

// ---------------------------------------------------------------------------
// bf16 MFMA GEMM: C[m,n] = epi( sum_k A[m,k]*W[n,k] ), fp32 accumulate.
// EPI: 0 fp32   2 +res fp32   3 bias+gelu -> bf16   4 bias+res fp32
//      6 plain bf16
// ---------------------------------------------------------------------------
template <int BMt, int BNt, int EPI>
__global__ __launch_bounds__(256) void bgemm_kernel(
    const ushort_t* __restrict__ A, const ushort_t* __restrict__ W,
    const float* __restrict__ bias, const float* __restrict__ res,
    float* __restrict__ C, ushort_t* __restrict__ Cb,
    int M, int N, int K) {
    constexpr int WM = BMt / 2, WN = BNt / 2;
    constexpr int MT = WM / 16, NT = WN / 16;
    constexpr int ACH = BMt * 4;            // 16B chunks in A tile
    constexpr int TOT = ACH + BNt * 4;
    __shared__ ushort_t As[BMt * 32];
    __shared__ ushort_t Ws[BNt * 32];

    int tid = threadIdx.x;
    int lane = tid & 63;
    int wv = tid >> 6;
    int wrow = wv >> 1, wcol = wv & 1;
    int m0 = blockIdx.y * BMt, n0 = blockIdx.x * BNt;
    int lrow = lane & 15;
    int ko = lane >> 4;

    f32x4 acc[MT][NT] = {};

    for (int k0 = 0; k0 < K; k0 += 32) {
#pragma unroll
        for (int i = 0; i < (TOT + 255) / 256; i++) {
            int e = tid + i * 256;
            if (e < TOT) {
                const ushort_t* gp;
                ushort_t* lp;
                if (e < ACH) {
                    int row = e >> 2, ch = e & 3;
                    gp = A + (size_t)(m0 + row) * K + k0 + ch * 8;
                    lp = As + e * 8;
                } else {
                    int e2 = e - ACH;
                    int row = e2 >> 2, ch = e2 & 3;
                    gp = W + (size_t)(n0 + row) * K + k0 + ch * 8;
                    lp = Ws + e2 * 8;
                }
                __builtin_amdgcn_global_load_lds(
                    (const __attribute__((address_space(1))) void*)gp,
                    (__attribute__((address_space(3))) void*)lp, 16, 0, 0);
            }
        }
        __syncthreads();
        short8 a[MT], b[NT];
#pragma unroll
        for (int mt = 0; mt < MT; mt++) {
            int ml = wrow * WM + mt * 16 + lrow;
            a[mt] = *(const short8*)(As + ml * 32 + ko * 8);
        }
#pragma unroll
        for (int nt = 0; nt < NT; nt++) {
            int nl = wcol * WN + nt * 16 + lrow;
            b[nt] = *(const short8*)(Ws + nl * 32 + ko * 8);
        }
#pragma unroll
        for (int mt = 0; mt < MT; mt++)
#pragma unroll
            for (int nt = 0; nt < NT; nt++)
                acc[mt][nt] = __builtin_amdgcn_mfma_f32_16x16x32_bf16(
                    a[mt], b[nt], acc[mt][nt], 0, 0, 0);
        __syncthreads();
    }

    int r4 = lane >> 4;
#pragma unroll
    for (int mt = 0; mt < MT; mt++) {
#pragma unroll
        for (int nt = 0; nt < NT; nt++) {
            int n = n0 + wcol * WN + nt * 16 + lrow;
#pragma unroll
            for (int i = 0; i < 4; i++) {
                int m = m0 + wrow * WM + mt * 16 + r4 * 4 + i;
                float v = acc[mt][nt][i];
                size_t off = (size_t)m * N + n;
                if (EPI == 0) {
                    C[off] = v;
                } else if (EPI == 2) {
                    C[off] = v + res[off];
                } else if (EPI == 3) {
                    float t = v + bias[n];
                    Cb[off] = bf16_rn(0.5f * t * (1.f + erff(t * 0.70710678118654752f)));
                } else if (EPI == 4) {
                    C[off] = v + bias[n] + res[off];
                } else if (EPI == 6) {
                    Cb[off] = bf16_rn(v);
                }
            }
        }
    }
}

// ---------------------------------------------------------------------------
// dtproj + softplus, fp32 VALU. Register-pressure-controlled rewrite:
// one column n per thread (w[32] + one acc live), ROLLED row loop over 64
// rows staged in LDS (wave-uniform broadcast reads), coalesced bf16 stores.
// Prev version unrolled 4 col-groups -> 256 VGPR + scratch spills (27 MB
// writes, 55 us). Grid (4, 64), block 256, ~48 VGPR target.
// ---------------------------------------------------------------------------
__global__ __launch_bounds__(256) void dt_kernel(
    const float* __restrict__ dbl, const float* __restrict__ wd,
    const float* __restrict__ bias, ushort_t* __restrict__ dt_b) {
    int tid = threadIdx.x;
    int n = blockIdx.x * 256 + tid;
    int m0 = blockIdx.y * 64;
    __shared__ float dtr[64][32];
#pragma unroll
    for (int i = 0; i < 2; i++) {
        int e = tid + i * 256;           // 0..511 over 64x8 float4
        int r = e >> 3, q = e & 7;
        *(float4*)&dtr[r][q * 4] = *(const float4*)(dbl + (size_t)(m0 + r) * 64 + q * 4);
    }
    __syncthreads();

    float w[32];
#pragma unroll
    for (int q = 0; q < 8; q++) {
        float4 v = *(const float4*)(wd + (size_t)n * 32 + q * 4);
        w[q * 4 + 0] = v.x; w[q * 4 + 1] = v.y;
        w[q * 4 + 2] = v.z; w[q * 4 + 3] = v.w;
    }
    float bn = bias[n];

    for (int r = 0; r < 64; r++) {       // rolled: keeps live set small
        float acc = bn;
#pragma unroll
        for (int k = 0; k < 32; k++) acc = fmaf(dtr[r][k], w[k], acc);
        float sp = (acc > 20.f) ? acc : log1pf(__expf(acc));
        dt_b[(size_t)(m0 + r) * D_INNER + n] = bf16_rn(sp);
    }
}

// ---------------------------------------------------------------------------
// Causal depthwise conv (width 4) + bias + SiLU. bf16 in (xz), bf16 out.
// ---------------------------------------------------------------------------
__global__ __launch_bounds__(256) void conv_silu_kernel(
    const ushort_t* __restrict__ xzb, const float* __restrict__ cw,
    const float* __restrict__ cb, ushort_t* __restrict__ xc_b) {
    int idx = blockIdx.x * 256 + threadIdx.x;  // 0 .. 4M-1
    int d = idx & (D_INNER - 1);
    int t = (idx >> 10) & (L_SEQ - 1);
    int b = idx >> 20;
    float acc = cb[d];
    const ushort_t* base = xzb + (size_t)(b * L_SEQ) * (2 * D_INNER) + d;
#pragma unroll
    for (int j = 0; j < 4; j++) {
        int tt = t - 3 + j;
        if (tt >= 0) acc += cw[d * 4 + j] * b2f(base[(size_t)tt * (2 * D_INNER)]);
    }
    float s = __fdividef(acc, 1.f + __expf(-acc));
    xc_b[idx] = bf16_rn(s);
}

// ---------------------------------------------------------------------------
// Chunked selective scan, d-per-lane: one lane per (b,chunk,d), 16 states in
// registers; B/C rows wave-uniform (scalar loads). dt/xc/z are bf16.
// ---------------------------------------------------------------------------
__global__ __launch_bounds__(256) void scan_pass1(
    const ushort_t* __restrict__ dt, const ushort_t* __restrict__ xc,
    const float* __restrict__ dbl, const float* __restrict__ A_log,
    float* __restrict__ Pbuf, float* __restrict__ Sbuf) {
    int tid = threadIdx.x;
    int blk = blockIdx.x;            // b*(NCHUNK*4) + c*4 + dg
    int dg = blk & 3;
    int c = (blk >> 2) & (NCHUNK - 1);
    int b = blk >> 7;
    int d = dg * 256 + tid;

    float A2[16], h[16], P[16];
    const float* ar = A_log + d * 16;
#pragma unroll
    for (int s = 0; s < 16; s++) {
        A2[s] = -__expf(ar[s]);
        h[s] = 0.f;
        P[s] = 1.f;
    }
    size_t rbase = (size_t)b * L_SEQ + (size_t)c * CHUNK;
    const ushort_t* dtp = dt + rbase * D_INNER + d;
    const ushort_t* xcp = xc + rbase * D_INNER + d;
    const float* blp = dbl + rbase * 64 + DT_RANK;   // B row (wave-uniform)

    float dtv = b2f(dtp[0]);
    float xcv = b2f(xcp[0]);
    float Ba[16], Bb[16];
#pragma unroll
    for (int s = 0; s < 16; s++) Ba[s] = blp[s];

    for (int t = 0; t < CHUNK; t += 2) {
        float dt1 = b2f(dtp[(size_t)(t + 1) * D_INNER]);
        float xc1 = b2f(xcp[(size_t)(t + 1) * D_INNER]);
#pragma unroll
        for (int s = 0; s < 16; s++) Bb[s] = blp[(t + 1) * 64 + s];
        {
            float u = dtv * xcv;
#pragma unroll
            for (int s = 0; s < 16; s++) {
                float a = __expf(dtv * A2[s]);
                h[s] = a * h[s] + u * Ba[s];
                P[s] *= a;
            }
        }
        float dt2 = 0.f, xc2 = 0.f;
        if (t + 2 < CHUNK) {
            dt2 = b2f(dtp[(size_t)(t + 2) * D_INNER]);
            xc2 = b2f(xcp[(size_t)(t + 2) * D_INNER]);
#pragma unroll
            for (int s = 0; s < 16; s++) Ba[s] = blp[(t + 2) * 64 + s];
        }
        {
            float u = dt1 * xc1;
#pragma unroll
            for (int s = 0; s < 16; s++) {
                float a = __expf(dt1 * A2[s]);
                h[s] = a * h[s] + u * Bb[s];
                P[s] *= a;
            }
        }
        dtv = dt2; xcv = xc2;
    }
    float* Pp = Pbuf + (((size_t)b * NCHUNK + c) * D_INNER + d) * 16;
    float* Sp = Sbuf + (((size_t)b * NCHUNK + c) * D_INNER + d) * 16;
#pragma unroll
    for (int q = 0; q < 4; q++) {
        *(float4*)(Pp + 4 * q) = make_float4(P[4 * q], P[4 * q + 1], P[4 * q + 2], P[4 * q + 3]);
        *(float4*)(Sp + 4 * q) = make_float4(h[4 * q], h[4 * q + 1], h[4 * q + 2], h[4 * q + 3]);
    }
}

// composes chunks; overwrites Pbuf[o] with Hin (incoming state) for chunk c.
__global__ __launch_bounds__(256) void scan_pass2(
    float* __restrict__ Pbuf, const float* __restrict__ Sbuf) {
    int idx = blockIdx.x * 256 + threadIdx.x;  // over B*D_INNER*D_STATE
    int sd = idx & 16383;
    int b = idx >> 14;
    float H = 0.f;
#pragma unroll
    for (int c = 0; c < NCHUNK; c++) {
        size_t o = ((size_t)(b * NCHUNK + c) << 14) + sd;
        float Pv = Pbuf[o];
        float Sv = Sbuf[o];
        Pbuf[o] = H;
        H = Pv * H + Sv;
    }
}

__global__ __launch_bounds__(256) void scan_pass3(
    const ushort_t* __restrict__ dt, const ushort_t* __restrict__ xc,
    const float* __restrict__ dbl, const ushort_t* __restrict__ xzb,
    const float* __restrict__ A_log, const float* __restrict__ Dsk,
    const float* __restrict__ Hin, ushort_t* __restrict__ y) {
    int tid = threadIdx.x;
    int blk = blockIdx.x;
    int dg = blk & 3;
    int c = (blk >> 2) & (NCHUNK - 1);
    int b = blk >> 7;
    int d = dg * 256 + tid;

    float A2[16], h[16];
    const float* ar = A_log + d * 16;
#pragma unroll
    for (int s = 0; s < 16; s++) A2[s] = -__expf(ar[s]);
    float Dv = Dsk[d];
    const float* Hp = Hin + (((size_t)b * NCHUNK + c) * D_INNER + d) * 16;
#pragma unroll
    for (int q = 0; q < 4; q++) {
        float4 hv = *(const float4*)(Hp + 4 * q);
        h[4 * q] = hv.x; h[4 * q + 1] = hv.y; h[4 * q + 2] = hv.z; h[4 * q + 3] = hv.w;
    }

    size_t rbase = (size_t)b * L_SEQ + (size_t)c * CHUNK;
    const ushort_t* dtp = dt + rbase * D_INNER + d;
    const ushort_t* xcp = xc + rbase * D_INNER + d;
    const float* blp = dbl + rbase * 64 + DT_RANK;   // [B(16) | C(16)] uniform
    const ushort_t* zp = xzb + rbase * (2 * D_INNER) + D_INNER + d;
    ushort_t* yp = y + rbase * D_INNER + d;

    float dtv = b2f(dtp[0]);
    float xcv = b2f(xcp[0]);
    float zv = b2f(zp[0]);
    float BCa[32], BCb[32];
#pragma unroll
    for (int s = 0; s < 32; s++) BCa[s] = blp[s];

    for (int t = 0; t < CHUNK; t += 2) {
        float dt1 = b2f(dtp[(size_t)(t + 1) * D_INNER]);
        float xc1 = b2f(xcp[(size_t)(t + 1) * D_INNER]);
        float z1 = b2f(zp[(size_t)(t + 1) * (2 * D_INNER)]);
#pragma unroll
        for (int s = 0; s < 32; s++) BCb[s] = blp[(t + 1) * 64 + s];
        {
            float u = dtv * xcv;
            float p = Dv * xcv;
#pragma unroll
            for (int s = 0; s < 16; s++) {
                float a = __expf(dtv * A2[s]);
                h[s] = a * h[s] + u * BCa[s];
                p = fmaf(h[s], BCa[16 + s], p);
            }
            float sig = __fdividef(zv, 1.f + __expf(-zv));
            yp[(size_t)t * D_INNER] = bf16_rn(p * sig);
        }
        float dt2 = 0.f, xc2 = 0.f, z2 = 0.f;
        if (t + 2 < CHUNK) {
            dt2 = b2f(dtp[(size_t)(t + 2) * D_INNER]);
            xc2 = b2f(xcp[(size_t)(t + 2) * D_INNER]);
            z2 = b2f(zp[(size_t)(t + 2) * (2 * D_INNER)]);
#pragma unroll
            for (int s = 0; s < 32; s++) BCa[s] = blp[(t + 2) * 64 + s];
        }
        {
            float u = dt1 * xc1;
            float p = Dv * xc1;
#pragma unroll
            for (int s = 0; s < 16; s++) {
                float a = __expf(dt1 * A2[s]);
                h[s] = a * h[s] + u * BCb[s];
                p = fmaf(h[s], BCb[16 + s], p);
            }
            float sig = __fdividef(z1, 1.f + __expf(-z1));
            yp[(size_t)(t + 1) * D_INNER] = bf16_rn(p * sig);
        }
        dtv = dt2; xcv = xc2; zv = z2;
    }
}

// ---------------------------------------------------------------------------
// Host launcher
// ---------------------------------------------------------------------------
extern "C" void kernel_launch(void* const* d_in, const int* in_sizes, int n_in,
                              void* d_out, int out_size, void* d_ws, size_t ws_size,
                              hipStream_t stream) {
    const float* x_in     = (const float*)d_in[0];
    const float* ln1_g    = (const float*)d_in[1];
    const float* ln1_b    = (const float*)d_in[2];
    const float* in_w     = (const float*)d_in[3];
    const float* conv_w   = (const float*)d_in[4];
    const float* conv_b   = (const float*)d_in[5];
    const float* xproj_w  = (const float*)d_in[6];
    const float* dtproj_w = (const float*)d_in[7];
    const float* dtproj_b = (const float*)d_in[8];
    const float* A_log    = (const float*)d_in[9];
    const float* D_skip   = (const float*)d_in[10];
    const float* out_w    = (const float*)d_in[11];
    const float* ln2_g    = (const float*)d_in[12];
    const float* ln2_b    = (const float*)d_in[13];
    const float* mlp_w1   = (const float*)d_in[14];
    const float* mlp_b1   = (const float*)d_in[15];
    const float* mlp_w2   = (const float*)d_in[16];
    const float* mlp_b2   = (const float*)d_in[17];

    char* p = (char*)d_ws;
    float* x_buf = (float*)p;        p += (size_t)NROWS * 512 * 4;            // 8 MB
    float* dbl   = (float*)p;        p += (size_t)NROWS * 64 * 4;             // 1 MB
    float* Pbuf  = (float*)p;        p += (size_t)BSZ * NCHUNK * 16384 * 4;   // 8 MB
    float* Sbuf  = (float*)p;        p += (size_t)BSZ * NCHUNK * 16384 * 4;   // 8 MB
    ushort_t* xz_b  = (ushort_t*)p;  p += (size_t)NROWS * 2048 * 2;           // 16 MB
    ushort_t* xn_b  = (ushort_t*)p;  p += (size_t)NROWS * 512 * 2;            // 4 MB
    ushort_t* xc_b  = (ushort_t*)p;  p += (size_t)NROWS * 1024 * 2;           // 8 MB
    ushort_t* dt_b  = (ushort_t*)p;  p += (size_t)NROWS * 1024 * 2;           // 8 MB
    ushort_t* yc_b  = (ushort_t*)p;  p += (size_t)NROWS * 1024 * 2;           // 8 MB
    ushort_t* wall  = (ushort_t*)p;  // contiguous weight block (order matters!)
    ushort_t* wi_b  = wall;                       // 5*2048*512
    ushort_t* wx_b  = wall + 5242880;             // 5*64*1024
    ushort_t* wo_b  = wall + 5570560;             // 5*512*1024
    ushort_t* w1_b  = wall + 8192000;             // 5*1024*512
    ushort_t* w2_b  = wall + 10813440;            // 5*512*1024
    ushort_t* h1_b  = xz_b;  // alias: xz dead once mlp1 runs

    // weights fp32 -> bf16, one dispatch (dtproj_w stays fp32)
    f2b_all_kernel<<<(F2B_TOT + 255) / 256, 256, 0, stream>>>(
        in_w, xproj_w, out_w, mlp_w1, mlp_w2, wall);

    for (int d = 0; d < 5; d++) {
        const float* xsrc = (d == 0) ? x_in : x_buf;

        // LN1 -> bf16
        ln_kernel<<<NROWS, 64, 0, stream>>>(xsrc, ln1_g + d * 512, ln1_b + d * 512, xn_b);
        // in_proj: 4096x2048, K=512 -> bf16 xz
        bgemm_kernel<128, 128, 6><<<dim3(16, 32), 256, 0, stream>>>(
            xn_b, wi_b + (size_t)d * 2048 * 512, nullptr, nullptr, nullptr, xz_b,
            NROWS, 2048, 512);
        // conv + silu -> bf16 xc
        conv_silu_kernel<<<(NROWS * D_INNER) / 256, 256, 0, stream>>>(
            xz_b, conv_w + d * 4096, conv_b + d * 1024, xc_b);
        // xproj: 4096x64, K=1024 -> fp32 dbl
        bgemm_kernel<32, 64, 0><<<dim3(1, 128), 256, 0, stream>>>(
            xc_b, wx_b + (size_t)d * 64 * 1024, nullptr, nullptr, dbl, nullptr,
            NROWS, 64, 1024);
        // dtproj + softplus (fp32 VALU, coalesced bf16 out)
        dt_kernel<<<dim3(4, 64), 256, 0, stream>>>(
            dbl, dtproj_w + (size_t)d * 1024 * 32, dtproj_b + d * 1024, dt_b);
        // chunked scan (d-per-lane)
        scan_pass1<<<BSZ * NCHUNK * 4, 256, 0, stream>>>(
            dt_b, xc_b, dbl, A_log + d * 16384, Pbuf, Sbuf);
        scan_pass2<<<(BSZ * D_INNER * D_STATE) / 256, 256, 0, stream>>>(Pbuf, Sbuf);
        scan_pass3<<<BSZ * NCHUNK * 4, 256, 0, stream>>>(
            dt_b, xc_b, dbl, xz_b, A_log + d * 16384, D_skip + d * 1024, Pbuf, yc_b);
        // out_proj + residual: 4096x512, K=1024 -> fp32 x_buf
        bgemm_kernel<128, 64, 2><<<dim3(8, 32), 256, 0, stream>>>(
            yc_b, wo_b + (size_t)d * 512 * 1024, nullptr, xsrc, x_buf, nullptr,
            NROWS, 512, 1024);
        // LN2 -> bf16
        ln_kernel<<<NROWS, 64, 0, stream>>>(x_buf, ln2_g + d * 512, ln2_b + d * 512, xn_b);
        // mlp1 + bias + gelu -> bf16 h1: 4096x1024, K=512
        bgemm_kernel<128, 128, 3><<<dim3(8, 32), 256, 0, stream>>>(
            xn_b, w1_b + (size_t)d * 1024 * 512, mlp_b1 + d * 1024, nullptr, nullptr, h1_b,
            NROWS, 1024, 512);
        // mlp2 + bias + residual: 4096x512, K=1024
        float* dst = (d == 4) ? (float*)d_out : x_buf;
        bgemm_kernel<128, 64, 4><<<dim3(8, 32), 256, 0, stream>>>(
            h1_b, w2_b + (size_t)d * 512 * 1024, mlp_b2 + d * 512, x_buf, dst, nullptr,
            NROWS, 512, 1024);
    }
}

// Round 9
// 1158.331 us; speedup vs baseline: 1.5418x; 1.0179x over previous
//
#include <hip/hip_runtime.h>
#include <math.h>

#define D_MODEL 512
#define D_INNER 1024
#define L_SEQ 1024
#define BSZ 4
#define NROWS (BSZ * L_SEQ) /* 4096 */
#define DT_RANK 32
#define D_STATE 16
#define CHUNK 32
#define NCHUNK (L_SEQ / CHUNK) /* 32 */

typedef unsigned short ushort_t;
typedef __attribute__((ext_vector_type(8))) short short8;
typedef __attribute__((ext_vector_type(4))) float f32x4;

__device__ inline ushort_t bf16_rn(float f) {
    union { float f; unsigned u; } v; v.f = f;
    unsigned r = v.u + 0x7fffu + ((v.u >> 16) & 1u);
    return (ushort_t)(r >> 16);
}
__device__ inline float b2f(ushort_t u) {
    union { unsigned u; float f; } v; v.u = (unsigned)u << 16; return v.f;
}

// ---------------------------------------------------------------------------
// Five weight tensors fp32 -> bf16 in ONE dispatch (dtproj_w stays fp32).
// Order in wall: in_w, xproj_w, out_w, mlp_w1, mlp_w2 (uint2 idx == i).
// ---------------------------------------------------------------------------
#define F2B_TOT 3358720  /* total float4 groups across the 5 tensors */
__global__ __launch_bounds__(256) void f2b_all_kernel(
    const float* __restrict__ w0, const float* __restrict__ w1,
    const float* __restrict__ w2, const float* __restrict__ w3,
    const float* __restrict__ w4, ushort_t* __restrict__ dst) {
    int i = blockIdx.x * 256 + threadIdx.x;
    if (i >= F2B_TOT) return;
    const float* src; int j;
    if (i < 1310720)      { src = w0; j = i; }
    else if (i < 1392640) { src = w1; j = i - 1310720; }
    else if (i < 2048000) { src = w2; j = i - 1392640; }
    else if (i < 2703360) { src = w3; j = i - 2048000; }
    else                  { src = w4; j = i - 2703360; }
    float4 v = ((const float4*)src)[j];
    uint2 pk;
    pk.x = (unsigned)bf16_rn(v.x) | ((unsigned)bf16_rn(v.y) << 16);
    pk.y = (unsigned)bf16_rn(v.z) | ((unsigned)bf16_rn(v.w) << 16);
    ((uint2*)dst)[i] = pk;
}

// ---------------------------------------------------------------------------
// LayerNorm: one wave per row of 512, bf16 output (feeds a GEMM)
// ---------------------------------------------------------------------------
__global__ __launch_bounds__(64) void ln_kernel(const float* __restrict__ x,
                                                const float* __restrict__ g,
                                                const float* __restrict__ b,
                                                ushort_t* __restrict__ out) {
    int row = blockIdx.x;
    int lane = threadIdx.x;
    const float* xr = x + (size_t)row * D_MODEL;
    float4 v0 = *(const float4*)(xr + lane * 8);
    float4 v1 = *(const float4*)(xr + lane * 8 + 4);
    float s = v0.x + v0.y + v0.z + v0.w + v1.x + v1.y + v1.z + v1.w;
    float ss = v0.x * v0.x + v0.y * v0.y + v0.z * v0.z + v0.w * v0.w +
               v1.x * v1.x + v1.y * v1.y + v1.z * v1.z + v1.w * v1.w;
#pragma unroll
    for (int o = 32; o >= 1; o >>= 1) {
        s += __shfl_xor(s, o);
        ss += __shfl_xor(ss, o);
    }
    float mean = s * (1.f / D_MODEL);
    float var = ss * (1.f / D_MODEL) - mean * mean;
    float rstd = rsqrtf(var + 1e-5f);
    float4 g0 = *(const float4*)(g + lane * 8);
    float4 g1 = *(const float4*)(g + lane * 8 + 4);
    float4 b0 = *(const float4*)(b + lane * 8);
    float4 b1 = *(const float4*)(b + lane * 8 + 4);
    float o0 = (v0.x - mean) * rstd * g0.x + b0.x;
    float o1 = (v0.y - mean) * rstd * g0.y + b0.y;
    float o2 = (v0.z - mean) * rstd * g0.z + b0.z;
    float o3 = (v0.w - mean) * rstd * g0.w + b0.w;
    float o4 = (v1.x - mean) * rstd * g1.x + b1.x;
    float o5 = (v1.y - mean) * rstd * g1.y + b1.y;
    float o6 = (v1.z - mean) * rstd * g1.z + b1.z;
    float o7 = (v1.w - mean) * rstd * g1.w + b1.w;
    uint4 pk;
    pk.x = (unsigned)bf16_rn(o0) | ((unsigned)bf16_rn(o1) << 16);
    pk.y = (unsigned)bf16_rn(o2) | ((unsigned)bf16_rn(o3) << 16);
    pk.z = (unsigned)bf16_rn(o4) | ((unsigned)bf16_rn(o5) << 16);
    pk.w = (unsigned)bf16_rn(o6) | ((unsigned)bf16_rn(o7) << 16);
    *(uint4*)(out + (size_t)row * D_MODEL + lane * 8) = pk;
}

// ---------------------------------------------------------------------------
// bf16 MFMA GEMM, BK=64. CRITICAL global_load_lds constraint (m104/m108):
// LDS deposit is wave-uniform-base + lane*16 — the linear lane order must BE
// the target layout. Chunks ordered e = hf*(rows*4) + row*4 + c2 so that
// lp = buf + e*8 lands data at [hf][row][32] — two back-to-back copies of
// the proven m97-style half-tile. One barrier pair per 64-wide K step
// (half the barriers of BK=32).
// EPI: 0 fp32   2 +res fp32   3 bias+gelu -> bf16   4 bias+res fp32
//      6 plain bf16
// ---------------------------------------------------------------------------
template <int BMt, int BNt, int EPI>
__global__ __launch_bounds__(256) void bgemm_kernel(
    const ushort_t* __restrict__ A, const ushort_t* __restrict__ W,
    const float* __restrict__ bias, const float* __restrict__ res,
    float* __restrict__ C, ushort_t* __restrict__ Cb,
    int M, int N, int K) {
    constexpr int WM = BMt / 2, WN = BNt / 2;
    constexpr int MT = WM / 16, NT = WN / 16;
    constexpr int ACH = BMt * 8;            // 16B chunks in A tile (BK=64)
    constexpr int TOT = ACH + BNt * 8;
    __shared__ ushort_t As[BMt * 64];       // [hf][BMt][32]
    __shared__ ushort_t Ws[BNt * 64];       // [hf][BNt][32]

    int tid = threadIdx.x;
    int lane = tid & 63;
    int wv = tid >> 6;
    int wrow = wv >> 1, wcol = wv & 1;
    int m0 = blockIdx.y * BMt, n0 = blockIdx.x * BNt;
    int lrow = lane & 15;
    int ko = lane >> 4;

    f32x4 acc[MT][NT] = {};

    for (int k0 = 0; k0 < K; k0 += 64) {
#pragma unroll
        for (int i = 0; i < (TOT + 255) / 256; i++) {
            int e = tid + i * 256;
            if (e < TOT) {
                const ushort_t* gp;
                ushort_t* lp;
                if (e < ACH) {
                    int hf = (e >= BMt * 4) ? 1 : 0;
                    int e2 = e - hf * (BMt * 4);
                    int row = e2 >> 2, c2 = e2 & 3;
                    gp = A + (size_t)(m0 + row) * K + k0 + hf * 32 + c2 * 8;
                    lp = As + e * 8;          // lane-contiguous == [hf][row][32]
                } else {
                    int e1 = e - ACH;
                    int hf = (e1 >= BNt * 4) ? 1 : 0;
                    int e2 = e1 - hf * (BNt * 4);
                    int row = e2 >> 2, c2 = e2 & 3;
                    gp = W + (size_t)(n0 + row) * K + k0 + hf * 32 + c2 * 8;
                    lp = Ws + e1 * 8;
                }
                __builtin_amdgcn_global_load_lds(
                    (const __attribute__((address_space(1))) void*)gp,
                    (__attribute__((address_space(3))) void*)lp, 16, 0, 0);
            }
        }
        __syncthreads();
#pragma unroll
        for (int hf = 0; hf < 2; hf++) {
            short8 a[MT], b[NT];
#pragma unroll
            for (int mt = 0; mt < MT; mt++) {
                int ml = wrow * WM + mt * 16 + lrow;
                a[mt] = *(const short8*)(As + hf * (BMt * 32) + ml * 32 + ko * 8);
            }
#pragma unroll
            for (int nt = 0; nt < NT; nt++) {
                int nl = wcol * WN + nt * 16 + lrow;
                b[nt] = *(const short8*)(Ws + hf * (BNt * 32) + nl * 32 + ko * 8);
            }
#pragma unroll
            for (int mt = 0; mt < MT; mt++)
#pragma unroll
                for (int nt = 0; nt < NT; nt++)
                    acc[mt][nt] = __builtin_amdgcn_mfma_f32_16x16x32_bf16(
                        a[mt], b[nt], acc[mt][nt], 0, 0, 0);
        }
        __syncthreads();
    }

    int r4 = lane >> 4;
#pragma unroll
    for (int mt = 0; mt < MT; mt++) {
#pragma unroll
        for (int nt = 0; nt < NT; nt++) {
            int n = n0 + wcol * WN + nt * 16 + lrow;
#pragma unroll
            for (int i = 0; i < 4; i++) {
                int m = m0 + wrow * WM + mt * 16 + r4 * 4 + i;
                float v = acc[mt][nt][i];
                size_t off = (size_t)m * N + n;
                if (EPI == 0) {
                    C[off] = v;
                } else if (EPI == 2) {
                    C[off] = v + res[off];
                } else if (EPI == 3) {
                    float t = v + bias[n];
                    Cb[off] = bf16_rn(0.5f * t * (1.f + erff(t * 0.70710678118654752f)));
                } else if (EPI == 4) {
                    C[off] = v + bias[n] + res[off];
                } else if (EPI == 6) {
                    Cb[off] = bf16_rn(v);
                }
            }
        }
    }
}

// ---------------------------------------------------------------------------
// dtproj + softplus, fp32 VALU (K=32 — MFMA wrong tool). One column n per
// thread, rolled row loop over 64 LDS-staged rows, coalesced bf16 stores.
// ---------------------------------------------------------------------------
__global__ __launch_bounds__(256) void dt_kernel(
    const float* __restrict__ dbl, const float* __restrict__ wd,
    const float* __restrict__ bias, ushort_t* __restrict__ dt_b) {
    int tid = threadIdx.x;
    int n = blockIdx.x * 256 + tid;
    int m0 = blockIdx.y * 64;
    __shared__ float dtr[64][32];
#pragma unroll
    for (int i = 0; i < 2; i++) {
        int e = tid + i * 256;           // 0..511 over 64x8 float4
        int r = e >> 3, q = e & 7;
        *(float4*)&dtr[r][q * 4] = *(const float4*)(dbl + (size_t)(m0 + r) * 64 + q * 4);
    }
    __syncthreads();

    float w[32];
#pragma unroll
    for (int q = 0; q < 8; q++) {
        float4 v = *(const float4*)(wd + (size_t)n * 32 + q * 4);
        w[q * 4 + 0] = v.x; w[q * 4 + 1] = v.y;
        w[q * 4 + 2] = v.z; w[q * 4 + 3] = v.w;
    }
    float bn = bias[n];

    for (int r = 0; r < 64; r++) {       // rolled: keeps live set small
        float acc = bn;
#pragma unroll
        for (int k = 0; k < 32; k++) acc = fmaf(dtr[r][k], w[k], acc);
        float sp = (acc > 20.f) ? acc : log1pf(__expf(acc));
        dt_b[(size_t)(m0 + r) * D_INNER + n] = bf16_rn(sp);
    }
}

// ---------------------------------------------------------------------------
// Causal depthwise conv (width 4) + bias + SiLU. bf16 in (xz), bf16 out.
// ---------------------------------------------------------------------------
__global__ __launch_bounds__(256) void conv_silu_kernel(
    const ushort_t* __restrict__ xzb, const float* __restrict__ cw,
    const float* __restrict__ cb, ushort_t* __restrict__ xc_b) {
    int idx = blockIdx.x * 256 + threadIdx.x;  // 0 .. 4M-1
    int d = idx & (D_INNER - 1);
    int t = (idx >> 10) & (L_SEQ - 1);
    int b = idx >> 20;
    float acc = cb[d];
    const ushort_t* base = xzb + (size_t)(b * L_SEQ) * (2 * D_INNER) + d;
#pragma unroll
    for (int j = 0; j < 4; j++) {
        int tt = t - 3 + j;
        if (tt >= 0) acc += cw[d * 4 + j] * b2f(base[(size_t)tt * (2 * D_INNER)]);
    }
    float s = __fdividef(acc, 1.f + __expf(-acc));
    xc_b[idx] = bf16_rn(s);
}

// ---------------------------------------------------------------------------
// Chunked selective scan, d-per-lane: one lane per (b,chunk,d), 16 states in
// registers; B/C rows wave-uniform (scalar loads). dt/xc/z are bf16.
// ---------------------------------------------------------------------------
__global__ __launch_bounds__(256) void scan_pass1(
    const ushort_t* __restrict__ dt, const ushort_t* __restrict__ xc,
    const float* __restrict__ dbl, const float* __restrict__ A_log,
    float* __restrict__ Pbuf, float* __restrict__ Sbuf) {
    int tid = threadIdx.x;
    int blk = blockIdx.x;            // b*(NCHUNK*4) + c*4 + dg
    int dg = blk & 3;
    int c = (blk >> 2) & (NCHUNK - 1);
    int b = blk >> 7;
    int d = dg * 256 + tid;

    float A2[16], h[16], P[16];
    const float* ar = A_log + d * 16;
#pragma unroll
    for (int s = 0; s < 16; s++) {
        A2[s] = -__expf(ar[s]);
        h[s] = 0.f;
        P[s] = 1.f;
    }
    size_t rbase = (size_t)b * L_SEQ + (size_t)c * CHUNK;
    const ushort_t* dtp = dt + rbase * D_INNER + d;
    const ushort_t* xcp = xc + rbase * D_INNER + d;
    const float* blp = dbl + rbase * 64 + DT_RANK;   // B row (wave-uniform)

    float dtv = b2f(dtp[0]);
    float xcv = b2f(xcp[0]);
    float Ba[16], Bb[16];
#pragma unroll
    for (int s = 0; s < 16; s++) Ba[s] = blp[s];

    for (int t = 0; t < CHUNK; t += 2) {
        float dt1 = b2f(dtp[(size_t)(t + 1) * D_INNER]);
        float xc1 = b2f(xcp[(size_t)(t + 1) * D_INNER]);
#pragma unroll
        for (int s = 0; s < 16; s++) Bb[s] = blp[(t + 1) * 64 + s];
        {
            float u = dtv * xcv;
#pragma unroll
            for (int s = 0; s < 16; s++) {
                float a = __expf(dtv * A2[s]);
                h[s] = a * h[s] + u * Ba[s];
                P[s] *= a;
            }
        }
        float dt2 = 0.f, xc2 = 0.f;
        if (t + 2 < CHUNK) {
            dt2 = b2f(dtp[(size_t)(t + 2) * D_INNER]);
            xc2 = b2f(xcp[(size_t)(t + 2) * D_INNER]);
#pragma unroll
            for (int s = 0; s < 16; s++) Ba[s] = blp[(t + 2) * 64 + s];
        }
        {
            float u = dt1 * xc1;
#pragma unroll
            for (int s = 0; s < 16; s++) {
                float a = __expf(dt1 * A2[s]);
                h[s] = a * h[s] + u * Bb[s];
                P[s] *= a;
            }
        }
        dtv = dt2; xcv = xc2;
    }
    float* Pp = Pbuf + (((size_t)b * NCHUNK + c) * D_INNER + d) * 16;
    float* Sp = Sbuf + (((size_t)b * NCHUNK + c) * D_INNER + d) * 16;
#pragma unroll
    for (int q = 0; q < 4; q++) {
        *(float4*)(Pp + 4 * q) = make_float4(P[4 * q], P[4 * q + 1], P[4 * q + 2], P[4 * q + 3]);
        *(float4*)(Sp + 4 * q) = make_float4(h[4 * q], h[4 * q + 1], h[4 * q + 2], h[4 * q + 3]);
    }
}

// composes chunks; overwrites Pbuf[o] with Hin (incoming state) for chunk c.
__global__ __launch_bounds__(256) void scan_pass2(
    float* __restrict__ Pbuf, const float* __restrict__ Sbuf) {
    int idx = blockIdx.x * 256 + threadIdx.x;  // over B*D_INNER*D_STATE
    int sd = idx & 16383;
    int b = idx >> 14;
    float H = 0.f;
#pragma unroll
    for (int c = 0; c < NCHUNK; c++) {
        size_t o = ((size_t)(b * NCHUNK + c) << 14) + sd;
        float Pv = Pbuf[o];
        float Sv = Sbuf[o];
        Pbuf[o] = H;
        H = Pv * H + Sv;
    }
}

__global__ __launch_bounds__(256) void scan_pass3(
    const ushort_t* __restrict__ dt, const ushort_t* __restrict__ xc,
    const float* __restrict__ dbl, const ushort_t* __restrict__ xzb,
    const float* __restrict__ A_log, const float* __restrict__ Dsk,
    const float* __restrict__ Hin, ushort_t* __restrict__ y) {
    int tid = threadIdx.x;
    int blk = blockIdx.x;
    int dg = blk & 3;
    int c = (blk >> 2) & (NCHUNK - 1);
    int b = blk >> 7;
    int d = dg * 256 + tid;

    float A2[16], h[16];
    const float* ar = A_log + d * 16;
#pragma unroll
    for (int s = 0; s < 16; s++) A2[s] = -__expf(ar[s]);
    float Dv = Dsk[d];
    const float* Hp = Hin + (((size_t)b * NCHUNK + c) * D_INNER + d) * 16;
#pragma unroll
    for (int q = 0; q < 4; q++) {
        float4 hv = *(const float4*)(Hp + 4 * q);
        h[4 * q] = hv.x; h[4 * q + 1] = hv.y; h[4 * q + 2] = hv.z; h[4 * q + 3] = hv.w;
    }

    size_t rbase = (size_t)b * L_SEQ + (size_t)c * CHUNK;
    const ushort_t* dtp = dt + rbase * D_INNER + d;
    const ushort_t* xcp = xc + rbase * D_INNER + d;
    const float* blp = dbl + rbase * 64 + DT_RANK;   // [B(16) | C(16)] uniform
    const ushort_t* zp = xzb + rbase * (2 * D_INNER) + D_INNER + d;
    ushort_t* yp = y + rbase * D_INNER + d;

    float dtv = b2f(dtp[0]);
    float xcv = b2f(xcp[0]);
    float zv = b2f(zp[0]);
    float BCa[32], BCb[32];
#pragma unroll
    for (int s = 0; s < 32; s++) BCa[s] = blp[s];

    for (int t = 0; t < CHUNK; t += 2) {
        float dt1 = b2f(dtp[(size_t)(t + 1) * D_INNER]);
        float xc1 = b2f(xcp[(size_t)(t + 1) * D_INNER]);
        float z1 = b2f(zp[(size_t)(t + 1) * (2 * D_INNER)]);
#pragma unroll
        for (int s = 0; s < 32; s++) BCb[s] = blp[(t + 1) * 64 + s];
        {
            float u = dtv * xcv;
            float p = Dv * xcv;
#pragma unroll
            for (int s = 0; s < 16; s++) {
                float a = __expf(dtv * A2[s]);
                h[s] = a * h[s] + u * BCa[s];
                p = fmaf(h[s], BCa[16 + s], p);
            }
            float sig = __fdividef(zv, 1.f + __expf(-zv));
            yp[(size_t)t * D_INNER] = bf16_rn(p * sig);
        }
        float dt2 = 0.f, xc2 = 0.f, z2 = 0.f;
        if (t + 2 < CHUNK) {
            dt2 = b2f(dtp[(size_t)(t + 2) * D_INNER]);
            xc2 = b2f(xcp[(size_t)(t + 2) * D_INNER]);
            z2 = b2f(zp[(size_t)(t + 2) * (2 * D_INNER)]);
#pragma unroll
            for (int s = 0; s < 32; s++) BCa[s] = blp[(t + 2) * 64 + s];
        }
        {
            float u = dt1 * xc1;
            float p = Dv * xc1;
#pragma unroll
            for (int s = 0; s < 16; s++) {
                float a = __expf(dt1 * A2[s]);
                h[s] = a * h[s] + u * BCb[s];
                p = fmaf(h[s], BCb[16 + s], p);
            }
            float sig = __fdividef(z1, 1.f + __expf(-z1));
            yp[(size_t)(t + 1) * D_INNER] = bf16_rn(p * sig);
        }
        dtv = dt2; xcv = xc2; zv = z2;
    }
}

// ---------------------------------------------------------------------------
// Host launcher
// ---------------------------------------------------------------------------
extern "C" void kernel_launch(void* const* d_in, const int* in_sizes, int n_in,
                              void* d_out, int out_size, void* d_ws, size_t ws_size,
                              hipStream_t stream) {
    const float* x_in     = (const float*)d_in[0];
    const float* ln1_g    = (const float*)d_in[1];
    const float* ln1_b    = (const float*)d_in[2];
    const float* in_w     = (const float*)d_in[3];
    const float* conv_w   = (const float*)d_in[4];
    const float* conv_b   = (const float*)d_in[5];
    const float* xproj_w  = (const float*)d_in[6];
    const float* dtproj_w = (const float*)d_in[7];
    const float* dtproj_b = (const float*)d_in[8];
    const float* A_log    = (const float*)d_in[9];
    const float* D_skip   = (const float*)d_in[10];
    const float* out_w    = (const float*)d_in[11];
    const float* ln2_g    = (const float*)d_in[12];
    const float* ln2_b    = (const float*)d_in[13];
    const float* mlp_w1   = (const float*)d_in[14];
    const float* mlp_b1   = (const float*)d_in[15];
    const float* mlp_w2   = (const float*)d_in[16];
    const float* mlp_b2   = (const float*)d_in[17];

    char* p = (char*)d_ws;
    float* x_buf = (float*)p;        p += (size_t)NROWS * 512 * 4;            // 8 MB
    float* dbl   = (float*)p;        p += (size_t)NROWS * 64 * 4;             // 1 MB
    float* Pbuf  = (float*)p;        p += (size_t)BSZ * NCHUNK * 16384 * 4;   // 8 MB
    float* Sbuf  = (float*)p;        p += (size_t)BSZ * NCHUNK * 16384 * 4;   // 8 MB
    ushort_t* xz_b  = (ushort_t*)p;  p += (size_t)NROWS * 2048 * 2;           // 16 MB
    ushort_t* xn_b  = (ushort_t*)p;  p += (size_t)NROWS * 512 * 2;            // 4 MB
    ushort_t* xc_b  = (ushort_t*)p;  p += (size_t)NROWS * 1024 * 2;           // 8 MB
    ushort_t* dt_b  = (ushort_t*)p;  p += (size_t)NROWS * 1024 * 2;           // 8 MB
    ushort_t* yc_b  = (ushort_t*)p;  p += (size_t)NROWS * 1024 * 2;           // 8 MB
    ushort_t* wall  = (ushort_t*)p;  // contiguous weight block (order matters!)
    ushort_t* wi_b  = wall;                       // 5*2048*512
    ushort_t* wx_b  = wall + 5242880;             // 5*64*1024
    ushort_t* wo_b  = wall + 5570560;             // 5*512*1024
    ushort_t* w1_b  = wall + 8192000;             // 5*1024*512
    ushort_t* w2_b  = wall + 10813440;            // 5*512*1024
    ushort_t* h1_b  = xz_b;  // alias: xz dead once mlp1 runs

    // weights fp32 -> bf16, one dispatch (dtproj_w stays fp32)
    f2b_all_kernel<<<(F2B_TOT + 255) / 256, 256, 0, stream>>>(
        in_w, xproj_w, out_w, mlp_w1, mlp_w2, wall);

    for (int d = 0; d < 5; d++) {
        const float* xsrc = (d == 0) ? x_in : x_buf;

        // LN1 -> bf16
        ln_kernel<<<NROWS, 64, 0, stream>>>(xsrc, ln1_g + d * 512, ln1_b + d * 512, xn_b);
        // in_proj: 4096x2048, K=512 -> bf16 xz
        bgemm_kernel<128, 128, 6><<<dim3(16, 32), 256, 0, stream>>>(
            xn_b, wi_b + (size_t)d * 2048 * 512, nullptr, nullptr, nullptr, xz_b,
            NROWS, 2048, 512);
        // conv + silu -> bf16 xc
        conv_silu_kernel<<<(NROWS * D_INNER) / 256, 256, 0, stream>>>(
            xz_b, conv_w + d * 4096, conv_b + d * 1024, xc_b);
        // xproj: 4096x64, K=1024 -> fp32 dbl
        bgemm_kernel<32, 64, 0><<<dim3(1, 128), 256, 0, stream>>>(
            xc_b, wx_b + (size_t)d * 64 * 1024, nullptr, nullptr, dbl, nullptr,
            NROWS, 64, 1024);
        // dtproj + softplus (fp32 VALU, coalesced bf16 out)
        dt_kernel<<<dim3(4, 64), 256, 0, stream>>>(
            dbl, dtproj_w + (size_t)d * 1024 * 32, dtproj_b + d * 1024, dt_b);
        // chunked scan (d-per-lane)
        scan_pass1<<<BSZ * NCHUNK * 4, 256, 0, stream>>>(
            dt_b, xc_b, dbl, A_log + d * 16384, Pbuf, Sbuf);
        scan_pass2<<<(BSZ * D_INNER * D_STATE) / 256, 256, 0, stream>>>(Pbuf, Sbuf);
        scan_pass3<<<BSZ * NCHUNK * 4, 256, 0, stream>>>(
            dt_b, xc_b, dbl, xz_b, A_log + d * 16384, D_skip + d * 1024, Pbuf, yc_b);
        // out_proj + residual: 4096x512, K=1024 -> fp32 x_buf
        bgemm_kernel<128, 64, 2><<<dim3(8, 32), 256, 0, stream>>>(
            yc_b, wo_b + (size_t)d * 512 * 1024, nullptr, xsrc, x_buf, nullptr,
            NROWS, 512, 1024);
        // LN2 -> bf16
        ln_kernel<<<NROWS, 64, 0, stream>>>(x_buf, ln2_g + d * 512, ln2_b + d * 512, xn_b);
        // mlp1 + bias + gelu -> bf16 h1: 4096x1024, K=512
        bgemm_kernel<128, 128, 3><<<dim3(8, 32), 256, 0, stream>>>(
            xn_b, w1_b + (size_t)d * 1024 * 512, mlp_b1 + d * 1024, nullptr, nullptr, h1_b,
            NROWS, 1024, 512);
        // mlp2 + bias + residual: 4096x512, K=1024
        float* dst = (d == 4) ? (float*)d_out : x_buf;
        bgemm_kernel<128, 64, 4><<<dim3(8, 32), 256, 0, stream>>>(
            h1_b, w2_b + (size_t)d * 512 * 1024, mlp_b2 + d * 512, x_buf, dst, nullptr,
            NROWS, 512, 1024);
    }
}

// Round 10
// 1084.754 us; speedup vs baseline: 1.6464x; 1.0678x over previous
//
#include <hip/hip_runtime.h>
#include <math.h>

#define D_MODEL 512
#define D_INNER 1024
#define L_SEQ 1024
#define BSZ 4
#define NROWS (BSZ * L_SEQ) /* 4096 */
#define DT_RANK 32
#define D_STATE 16
#define CHUNK 32
#define NCHUNK (L_SEQ / CHUNK) /* 32 */

typedef unsigned short ushort_t;
typedef __attribute__((ext_vector_type(8))) short short8;
typedef __attribute__((ext_vector_type(4))) float f32x4;

__device__ inline ushort_t bf16_rn(float f) {
    union { float f; unsigned u; } v; v.f = f;
    unsigned r = v.u + 0x7fffu + ((v.u >> 16) & 1u);
    return (ushort_t)(r >> 16);
}
__device__ inline float b2f(ushort_t u) {
    union { unsigned u; float f; } v; v.u = (unsigned)u << 16; return v.f;
}

// ---------------------------------------------------------------------------
// Five weight tensors fp32 -> bf16 in ONE dispatch (dtproj_w stays fp32).
// Order in wall: in_w, xproj_w, out_w, mlp_w1, mlp_w2 (uint2 idx == i).
// ---------------------------------------------------------------------------
#define F2B_TOT 3358720  /* total float4 groups across the 5 tensors */
__global__ __launch_bounds__(256) void f2b_all_kernel(
    const float* __restrict__ w0, const float* __restrict__ w1,
    const float* __restrict__ w2, const float* __restrict__ w3,
    const float* __restrict__ w4, ushort_t* __restrict__ dst) {
    int i = blockIdx.x * 256 + threadIdx.x;
    if (i >= F2B_TOT) return;
    const float* src; int j;
    if (i < 1310720)      { src = w0; j = i; }
    else if (i < 1392640) { src = w1; j = i - 1310720; }
    else if (i < 2048000) { src = w2; j = i - 1392640; }
    else if (i < 2703360) { src = w3; j = i - 2048000; }
    else                  { src = w4; j = i - 2703360; }
    float4 v = ((const float4*)src)[j];
    uint2 pk;
    pk.x = (unsigned)bf16_rn(v.x) | ((unsigned)bf16_rn(v.y) << 16);
    pk.y = (unsigned)bf16_rn(v.z) | ((unsigned)bf16_rn(v.w) << 16);
    ((uint2*)dst)[i] = pk;
}

// ---------------------------------------------------------------------------
// LayerNorm: one wave per row of 512, bf16 output (feeds a GEMM)
// ---------------------------------------------------------------------------
__global__ __launch_bounds__(64) void ln_kernel(const float* __restrict__ x,
                                                const float* __restrict__ g,
                                                const float* __restrict__ b,
                                                ushort_t* __restrict__ out) {
    int row = blockIdx.x;
    int lane = threadIdx.x;
    const float* xr = x + (size_t)row * D_MODEL;
    float4 v0 = *(const float4*)(xr + lane * 8);
    float4 v1 = *(const float4*)(xr + lane * 8 + 4);
    float s = v0.x + v0.y + v0.z + v0.w + v1.x + v1.y + v1.z + v1.w;
    float ss = v0.x * v0.x + v0.y * v0.y + v0.z * v0.z + v0.w * v0.w +
               v1.x * v1.x + v1.y * v1.y + v1.z * v1.z + v1.w * v1.w;
#pragma unroll
    for (int o = 32; o >= 1; o >>= 1) {
        s += __shfl_xor(s, o);
        ss += __shfl_xor(ss, o);
    }
    float mean = s * (1.f / D_MODEL);
    float var = ss * (1.f / D_MODEL) - mean * mean;
    float rstd = rsqrtf(var + 1e-5f);
    float4 g0 = *(const float4*)(g + lane * 8);
    float4 g1 = *(const float4*)(g + lane * 8 + 4);
    float4 b0 = *(const float4*)(b + lane * 8);
    float4 b1 = *(const float4*)(b + lane * 8 + 4);
    float o0 = (v0.x - mean) * rstd * g0.x + b0.x;
    float o1 = (v0.y - mean) * rstd * g0.y + b0.y;
    float o2 = (v0.z - mean) * rstd * g0.z + b0.z;
    float o3 = (v0.w - mean) * rstd * g0.w + b0.w;
    float o4 = (v1.x - mean) * rstd * g1.x + b1.x;
    float o5 = (v1.y - mean) * rstd * g1.y + b1.y;
    float o6 = (v1.z - mean) * rstd * g1.z + b1.z;
    float o7 = (v1.w - mean) * rstd * g1.w + b1.w;
    uint4 pk;
    pk.x = (unsigned)bf16_rn(o0) | ((unsigned)bf16_rn(o1) << 16);
    pk.y = (unsigned)bf16_rn(o2) | ((unsigned)bf16_rn(o3) << 16);
    pk.z = (unsigned)bf16_rn(o4) | ((unsigned)bf16_rn(o5) << 16);
    pk.w = (unsigned)bf16_rn(o6) | ((unsigned)bf16_rn(o7) << 16);
    *(uint4*)(out + (size_t)row * D_MODEL + lane * 8) = pk;
}

// ---------------------------------------------------------------------------
// bf16 MFMA GEMM, BK=64, [hf][row][32] LDS layout (lane-contiguous deposit —
// the only legal global_load_lds pattern, m104/m108). Tile sizes chosen per
// call site so grid >= 512 blocks (>=2 blocks/CU): 1 block/CU = 1 wave/SIMD
// leaves staging+barrier latency uncovered (round-9 finding).
// EPI: 0 fp32   2 +res fp32   3 bias+gelu -> bf16   4 bias+res fp32
//      6 plain bf16
// ---------------------------------------------------------------------------
template <int BMt, int BNt, int EPI>
__global__ __launch_bounds__(256) void bgemm_kernel(
    const ushort_t* __restrict__ A, const ushort_t* __restrict__ W,
    const float* __restrict__ bias, const float* __restrict__ res,
    float* __restrict__ C, ushort_t* __restrict__ Cb,
    int M, int N, int K) {
    constexpr int WM = BMt / 2, WN = BNt / 2;
    constexpr int MT = WM / 16, NT = WN / 16;
    constexpr int ACH = BMt * 8;            // 16B chunks in A tile (BK=64)
    constexpr int TOT = ACH + BNt * 8;
    __shared__ ushort_t As[BMt * 64];       // [hf][BMt][32]
    __shared__ ushort_t Ws[BNt * 64];       // [hf][BNt][32]

    int tid = threadIdx.x;
    int lane = tid & 63;
    int wv = tid >> 6;
    int wrow = wv >> 1, wcol = wv & 1;
    int m0 = blockIdx.y * BMt, n0 = blockIdx.x * BNt;
    int lrow = lane & 15;
    int ko = lane >> 4;

    f32x4 acc[MT][NT] = {};

    for (int k0 = 0; k0 < K; k0 += 64) {
#pragma unroll
        for (int i = 0; i < (TOT + 255) / 256; i++) {
            int e = tid + i * 256;
            if (e < TOT) {
                const ushort_t* gp;
                ushort_t* lp;
                if (e < ACH) {
                    int hf = (e >= BMt * 4) ? 1 : 0;
                    int e2 = e - hf * (BMt * 4);
                    int row = e2 >> 2, c2 = e2 & 3;
                    gp = A + (size_t)(m0 + row) * K + k0 + hf * 32 + c2 * 8;
                    lp = As + e * 8;          // lane-contiguous == [hf][row][32]
                } else {
                    int e1 = e - ACH;
                    int hf = (e1 >= BNt * 4) ? 1 : 0;
                    int e2 = e1 - hf * (BNt * 4);
                    int row = e2 >> 2, c2 = e2 & 3;
                    gp = W + (size_t)(n0 + row) * K + k0 + hf * 32 + c2 * 8;
                    lp = Ws + e1 * 8;
                }
                __builtin_amdgcn_global_load_lds(
                    (const __attribute__((address_space(1))) void*)gp,
                    (__attribute__((address_space(3))) void*)lp, 16, 0, 0);
            }
        }
        __syncthreads();
#pragma unroll
        for (int hf = 0; hf < 2; hf++) {
            short8 a[MT], b[NT];
#pragma unroll
            for (int mt = 0; mt < MT; mt++) {
                int ml = wrow * WM + mt * 16 + lrow;
                a[mt] = *(const short8*)(As + hf * (BMt * 32) + ml * 32 + ko * 8);
            }
#pragma unroll
            for (int nt = 0; nt < NT; nt++) {
                int nl = wcol * WN + nt * 16 + lrow;
                b[nt] = *(const short8*)(Ws + hf * (BNt * 32) + nl * 32 + ko * 8);
            }
#pragma unroll
            for (int mt = 0; mt < MT; mt++)
#pragma unroll
                for (int nt = 0; nt < NT; nt++)
                    acc[mt][nt] = __builtin_amdgcn_mfma_f32_16x16x32_bf16(
                        a[mt], b[nt], acc[mt][nt], 0, 0, 0);
        }
        __syncthreads();
    }

    int r4 = lane >> 4;
#pragma unroll
    for (int mt = 0; mt < MT; mt++) {
#pragma unroll
        for (int nt = 0; nt < NT; nt++) {
            int n = n0 + wcol * WN + nt * 16 + lrow;
#pragma unroll
            for (int i = 0; i < 4; i++) {
                int m = m0 + wrow * WM + mt * 16 + r4 * 4 + i;
                float v = acc[mt][nt][i];
                size_t off = (size_t)m * N + n;
                if (EPI == 0) {
                    C[off] = v;
                } else if (EPI == 2) {
                    C[off] = v + res[off];
                } else if (EPI == 3) {
                    float t = v + bias[n];
                    Cb[off] = bf16_rn(0.5f * t * (1.f + erff(t * 0.70710678118654752f)));
                } else if (EPI == 4) {
                    C[off] = v + bias[n] + res[off];
                } else if (EPI == 6) {
                    Cb[off] = bf16_rn(v);
                }
            }
        }
    }
}

// ---------------------------------------------------------------------------
// dtproj + softplus, fp32 VALU (K=32 — MFMA wrong tool). One column n per
// thread, rolled row loop over 64 LDS-staged rows, coalesced bf16 stores.
// ---------------------------------------------------------------------------
__global__ __launch_bounds__(256) void dt_kernel(
    const float* __restrict__ dbl, const float* __restrict__ wd,
    const float* __restrict__ bias, ushort_t* __restrict__ dt_b) {
    int tid = threadIdx.x;
    int n = blockIdx.x * 256 + tid;
    int m0 = blockIdx.y * 64;
    __shared__ float dtr[64][32];
#pragma unroll
    for (int i = 0; i < 2; i++) {
        int e = tid + i * 256;           // 0..511 over 64x8 float4
        int r = e >> 3, q = e & 7;
        *(float4*)&dtr[r][q * 4] = *(const float4*)(dbl + (size_t)(m0 + r) * 64 + q * 4);
    }
    __syncthreads();

    float w[32];
#pragma unroll
    for (int q = 0; q < 8; q++) {
        float4 v = *(const float4*)(wd + (size_t)n * 32 + q * 4);
        w[q * 4 + 0] = v.x; w[q * 4 + 1] = v.y;
        w[q * 4 + 2] = v.z; w[q * 4 + 3] = v.w;
    }
    float bn = bias[n];

    for (int r = 0; r < 64; r++) {       // rolled: keeps live set small
        float acc = bn;
#pragma unroll
        for (int k = 0; k < 32; k++) acc = fmaf(dtr[r][k], w[k], acc);
        float sp = (acc > 20.f) ? acc : log1pf(__expf(acc));
        dt_b[(size_t)(m0 + r) * D_INNER + n] = bf16_rn(sp);
    }
}

// ---------------------------------------------------------------------------
// Causal depthwise conv (width 4) + bias + SiLU. bf16 in (xz), bf16 out.
// ---------------------------------------------------------------------------
__global__ __launch_bounds__(256) void conv_silu_kernel(
    const ushort_t* __restrict__ xzb, const float* __restrict__ cw,
    const float* __restrict__ cb, ushort_t* __restrict__ xc_b) {
    int idx = blockIdx.x * 256 + threadIdx.x;  // 0 .. 4M-1
    int d = idx & (D_INNER - 1);
    int t = (idx >> 10) & (L_SEQ - 1);
    int b = idx >> 20;
    float acc = cb[d];
    const ushort_t* base = xzb + (size_t)(b * L_SEQ) * (2 * D_INNER) + d;
#pragma unroll
    for (int j = 0; j < 4; j++) {
        int tt = t - 3 + j;
        if (tt >= 0) acc += cw[d * 4 + j] * b2f(base[(size_t)tt * (2 * D_INNER)]);
    }
    float s = __fdividef(acc, 1.f + __expf(-acc));
    xc_b[idx] = bf16_rn(s);
}

// ---------------------------------------------------------------------------
// Chunked selective scan, d-per-lane: one lane per (b,chunk,d), 16 states in
// registers; B/C rows wave-uniform (scalar loads). dt/xc/z are bf16.
// ---------------------------------------------------------------------------
__global__ __launch_bounds__(256) void scan_pass1(
    const ushort_t* __restrict__ dt, const ushort_t* __restrict__ xc,
    const float* __restrict__ dbl, const float* __restrict__ A_log,
    float* __restrict__ Pbuf, float* __restrict__ Sbuf) {
    int tid = threadIdx.x;
    int blk = blockIdx.x;            // b*(NCHUNK*4) + c*4 + dg
    int dg = blk & 3;
    int c = (blk >> 2) & (NCHUNK - 1);
    int b = blk >> 7;
    int d = dg * 256 + tid;

    float A2[16], h[16], P[16];
    const float* ar = A_log + d * 16;
#pragma unroll
    for (int s = 0; s < 16; s++) {
        A2[s] = -__expf(ar[s]);
        h[s] = 0.f;
        P[s] = 1.f;
    }
    size_t rbase = (size_t)b * L_SEQ + (size_t)c * CHUNK;
    const ushort_t* dtp = dt + rbase * D_INNER + d;
    const ushort_t* xcp = xc + rbase * D_INNER + d;
    const float* blp = dbl + rbase * 64 + DT_RANK;   // B row (wave-uniform)

    float dtv = b2f(dtp[0]);
    float xcv = b2f(xcp[0]);
    float Ba[16], Bb[16];
#pragma unroll
    for (int s = 0; s < 16; s++) Ba[s] = blp[s];

    for (int t = 0; t < CHUNK; t += 2) {
        float dt1 = b2f(dtp[(size_t)(t + 1) * D_INNER]);
        float xc1 = b2f(xcp[(size_t)(t + 1) * D_INNER]);
#pragma unroll
        for (int s = 0; s < 16; s++) Bb[s] = blp[(t + 1) * 64 + s];
        {
            float u = dtv * xcv;
#pragma unroll
            for (int s = 0; s < 16; s++) {
                float a = __expf(dtv * A2[s]);
                h[s] = a * h[s] + u * Ba[s];
                P[s] *= a;
            }
        }
        float dt2 = 0.f, xc2 = 0.f;
        if (t + 2 < CHUNK) {
            dt2 = b2f(dtp[(size_t)(t + 2) * D_INNER]);
            xc2 = b2f(xcp[(size_t)(t + 2) * D_INNER]);
#pragma unroll
            for (int s = 0; s < 16; s++) Ba[s] = blp[(t + 2) * 64 + s];
        }
        {
            float u = dt1 * xc1;
#pragma unroll
            for (int s = 0; s < 16; s++) {
                float a = __expf(dt1 * A2[s]);
                h[s] = a * h[s] + u * Bb[s];
                P[s] *= a;
            }
        }
        dtv = dt2; xcv = xc2;
    }
    float* Pp = Pbuf + (((size_t)b * NCHUNK + c) * D_INNER + d) * 16;
    float* Sp = Sbuf + (((size_t)b * NCHUNK + c) * D_INNER + d) * 16;
#pragma unroll
    for (int q = 0; q < 4; q++) {
        *(float4*)(Pp + 4 * q) = make_float4(P[4 * q], P[4 * q + 1], P[4 * q + 2], P[4 * q + 3]);
        *(float4*)(Sp + 4 * q) = make_float4(h[4 * q], h[4 * q + 1], h[4 * q + 2], h[4 * q + 3]);
    }
}

// composes chunks; overwrites Pbuf[o] with Hin (incoming state) for chunk c.
__global__ __launch_bounds__(256) void scan_pass2(
    float* __restrict__ Pbuf, const float* __restrict__ Sbuf) {
    int idx = blockIdx.x * 256 + threadIdx.x;  // over B*D_INNER*D_STATE
    int sd = idx & 16383;
    int b = idx >> 14;
    float H = 0.f;
#pragma unroll
    for (int c = 0; c < NCHUNK; c++) {
        size_t o = ((size_t)(b * NCHUNK + c) << 14) + sd;
        float Pv = Pbuf[o];
        float Sv = Sbuf[o];
        Pbuf[o] = H;
        H = Pv * H + Sv;
    }
}

__global__ __launch_bounds__(256) void scan_pass3(
    const ushort_t* __restrict__ dt, const ushort_t* __restrict__ xc,
    const float* __restrict__ dbl, const ushort_t* __restrict__ xzb,
    const float* __restrict__ A_log, const float* __restrict__ Dsk,
    const float* __restrict__ Hin, ushort_t* __restrict__ y) {
    int tid = threadIdx.x;
    int blk = blockIdx.x;
    int dg = blk & 3;
    int c = (blk >> 2) & (NCHUNK - 1);
    int b = blk >> 7;
    int d = dg * 256 + tid;

    float A2[16], h[16];
    const float* ar = A_log + d * 16;
#pragma unroll
    for (int s = 0; s < 16; s++) A2[s] = -__expf(ar[s]);
    float Dv = Dsk[d];
    const float* Hp = Hin + (((size_t)b * NCHUNK + c) * D_INNER + d) * 16;
#pragma unroll
    for (int q = 0; q < 4; q++) {
        float4 hv = *(const float4*)(Hp + 4 * q);
        h[4 * q] = hv.x; h[4 * q + 1] = hv.y; h[4 * q + 2] = hv.z; h[4 * q + 3] = hv.w;
    }

    size_t rbase = (size_t)b * L_SEQ + (size_t)c * CHUNK;
    const ushort_t* dtp = dt + rbase * D_INNER + d;
    const ushort_t* xcp = xc + rbase * D_INNER + d;
    const float* blp = dbl + rbase * 64 + DT_RANK;   // [B(16) | C(16)] uniform
    const ushort_t* zp = xzb + rbase * (2 * D_INNER) + D_INNER + d;
    ushort_t* yp = y + rbase * D_INNER + d;

    float dtv = b2f(dtp[0]);
    float xcv = b2f(xcp[0]);
    float zv = b2f(zp[0]);
    float BCa[32], BCb[32];
#pragma unroll
    for (int s = 0; s < 32; s++) BCa[s] = blp[s];

    for (int t = 0; t < CHUNK; t += 2) {
        float dt1 = b2f(dtp[(size_t)(t + 1) * D_INNER]);
        float xc1 = b2f(xcp[(size_t)(t + 1) * D_INNER]);
        float z1 = b2f(zp[(size_t)(t + 1) * (2 * D_INNER)]);
#pragma unroll
        for (int s = 0; s < 32; s++) BCb[s] = blp[(t + 1) * 64 + s];
        {
            float u = dtv * xcv;
            float p = Dv * xcv;
#pragma unroll
            for (int s = 0; s < 16; s++) {
                float a = __expf(dtv * A2[s]);
                h[s] = a * h[s] + u * BCa[s];
                p = fmaf(h[s], BCa[16 + s], p);
            }
            float sig = __fdividef(zv, 1.f + __expf(-zv));
            yp[(size_t)t * D_INNER] = bf16_rn(p * sig);
        }
        float dt2 = 0.f, xc2 = 0.f, z2 = 0.f;
        if (t + 2 < CHUNK) {
            dt2 = b2f(dtp[(size_t)(t + 2) * D_INNER]);
            xc2 = b2f(xcp[(size_t)(t + 2) * D_INNER]);
            z2 = b2f(zp[(size_t)(t + 2) * (2 * D_INNER)]);
#pragma unroll
            for (int s = 0; s < 32; s++) BCa[s] = blp[(t + 2) * 64 + s];
        }
        {
            float u = dt1 * xc1;
            float p = Dv * xc1;
#pragma unroll
            for (int s = 0; s < 16; s++) {
                float a = __expf(dt1 * A2[s]);
                h[s] = a * h[s] + u * BCb[s];
                p = fmaf(h[s], BCb[16 + s], p);
            }
            float sig = __fdividef(z1, 1.f + __expf(-z1));
            yp[(size_t)(t + 1) * D_INNER] = bf16_rn(p * sig);
        }
        dtv = dt2; xcv = xc2; zv = z2;
    }
}

// ---------------------------------------------------------------------------
// Host launcher
// ---------------------------------------------------------------------------
extern "C" void kernel_launch(void* const* d_in, const int* in_sizes, int n_in,
                              void* d_out, int out_size, void* d_ws, size_t ws_size,
                              hipStream_t stream) {
    const float* x_in     = (const float*)d_in[0];
    const float* ln1_g    = (const float*)d_in[1];
    const float* ln1_b    = (const float*)d_in[2];
    const float* in_w     = (const float*)d_in[3];
    const float* conv_w   = (const float*)d_in[4];
    const float* conv_b   = (const float*)d_in[5];
    const float* xproj_w  = (const float*)d_in[6];
    const float* dtproj_w = (const float*)d_in[7];
    const float* dtproj_b = (const float*)d_in[8];
    const float* A_log    = (const float*)d_in[9];
    const float* D_skip   = (const float*)d_in[10];
    const float* out_w    = (const float*)d_in[11];
    const float* ln2_g    = (const float*)d_in[12];
    const float* ln2_b    = (const float*)d_in[13];
    const float* mlp_w1   = (const float*)d_in[14];
    const float* mlp_b1   = (const float*)d_in[15];
    const float* mlp_w2   = (const float*)d_in[16];
    const float* mlp_b2   = (const float*)d_in[17];

    char* p = (char*)d_ws;
    float* x_buf = (float*)p;        p += (size_t)NROWS * 512 * 4;            // 8 MB
    float* dbl   = (float*)p;        p += (size_t)NROWS * 64 * 4;             // 1 MB
    float* Pbuf  = (float*)p;        p += (size_t)BSZ * NCHUNK * 16384 * 4;   // 8 MB
    float* Sbuf  = (float*)p;        p += (size_t)BSZ * NCHUNK * 16384 * 4;   // 8 MB
    ushort_t* xz_b  = (ushort_t*)p;  p += (size_t)NROWS * 2048 * 2;           // 16 MB
    ushort_t* xn_b  = (ushort_t*)p;  p += (size_t)NROWS * 512 * 2;            // 4 MB
    ushort_t* xc_b  = (ushort_t*)p;  p += (size_t)NROWS * 1024 * 2;           // 8 MB
    ushort_t* dt_b  = (ushort_t*)p;  p += (size_t)NROWS * 1024 * 2;           // 8 MB
    ushort_t* yc_b  = (ushort_t*)p;  p += (size_t)NROWS * 1024 * 2;           // 8 MB
    ushort_t* wall  = (ushort_t*)p;  // contiguous weight block (order matters!)
    ushort_t* wi_b  = wall;                       // 5*2048*512
    ushort_t* wx_b  = wall + 5242880;             // 5*64*1024
    ushort_t* wo_b  = wall + 5570560;             // 5*512*1024
    ushort_t* w1_b  = wall + 8192000;             // 5*1024*512
    ushort_t* w2_b  = wall + 10813440;            // 5*512*1024
    ushort_t* h1_b  = xz_b;  // alias: xz dead once mlp1 runs

    // weights fp32 -> bf16, one dispatch (dtproj_w stays fp32)
    f2b_all_kernel<<<(F2B_TOT + 255) / 256, 256, 0, stream>>>(
        in_w, xproj_w, out_w, mlp_w1, mlp_w2, wall);

    for (int d = 0; d < 5; d++) {
        const float* xsrc = (d == 0) ? x_in : x_buf;

        // LN1 -> bf16
        ln_kernel<<<NROWS, 64, 0, stream>>>(xsrc, ln1_g + d * 512, ln1_b + d * 512, xn_b);
        // in_proj: 4096x2048, K=512 -> bf16 xz  (64x128 tile, 1024 blocks = 4/CU)
        bgemm_kernel<64, 128, 6><<<dim3(16, 64), 256, 0, stream>>>(
            xn_b, wi_b + (size_t)d * 2048 * 512, nullptr, nullptr, nullptr, xz_b,
            NROWS, 2048, 512);
        // conv + silu -> bf16 xc
        conv_silu_kernel<<<(NROWS * D_INNER) / 256, 256, 0, stream>>>(
            xz_b, conv_w + d * 4096, conv_b + d * 1024, xc_b);
        // xproj: 4096x64, K=1024 -> fp32 dbl
        bgemm_kernel<32, 64, 0><<<dim3(1, 128), 256, 0, stream>>>(
            xc_b, wx_b + (size_t)d * 64 * 1024, nullptr, nullptr, dbl, nullptr,
            NROWS, 64, 1024);
        // dtproj + softplus (fp32 VALU, coalesced bf16 out)
        dt_kernel<<<dim3(4, 64), 256, 0, stream>>>(
            dbl, dtproj_w + (size_t)d * 1024 * 32, dtproj_b + d * 1024, dt_b);
        // chunked scan (d-per-lane)
        scan_pass1<<<BSZ * NCHUNK * 4, 256, 0, stream>>>(
            dt_b, xc_b, dbl, A_log + d * 16384, Pbuf, Sbuf);
        scan_pass2<<<(BSZ * D_INNER * D_STATE) / 256, 256, 0, stream>>>(Pbuf, Sbuf);
        scan_pass3<<<BSZ * NCHUNK * 4, 256, 0, stream>>>(
            dt_b, xc_b, dbl, xz_b, A_log + d * 16384, D_skip + d * 1024, Pbuf, yc_b);
        // out_proj + residual: 4096x512, K=1024 -> fp32 x_buf  (64x64, 512 blocks)
        bgemm_kernel<64, 64, 2><<<dim3(8, 64), 256, 0, stream>>>(
            yc_b, wo_b + (size_t)d * 512 * 1024, nullptr, xsrc, x_buf, nullptr,
            NROWS, 512, 1024);
        // LN2 -> bf16
        ln_kernel<<<NROWS, 64, 0, stream>>>(x_buf, ln2_g + d * 512, ln2_b + d * 512, xn_b);
        // mlp1 + bias + gelu -> bf16 h1: 4096x1024, K=512  (64x128, 512 blocks)
        bgemm_kernel<64, 128, 3><<<dim3(8, 64), 256, 0, stream>>>(
            xn_b, w1_b + (size_t)d * 1024 * 512, mlp_b1 + d * 1024, nullptr, nullptr, h1_b,
            NROWS, 1024, 512);
        // mlp2 + bias + residual: 4096x512, K=1024  (64x64, 512 blocks)
        float* dst = (d == 4) ? (float*)d_out : x_buf;
        bgemm_kernel<64, 64, 4><<<dim3(8, 64), 256, 0, stream>>>(
            h1_b, w2_b + (size_t)d * 512 * 1024, mlp_b2 + d * 512, x_buf, dst, nullptr,
            NROWS, 512, 1024);
    }
}